// Round 1
// baseline (2366.094 us; speedup 1.0000x reference)
//
#include <hip/hip_runtime.h>
#include <cmath>

// Problem constants (hard-coded from setup_inputs: b=2, c=128)
constexpr int BT = 16, Bb = 2, Tt = 8, Dc = 128, PIX = 4096; // 64x64 images

// ---------------------------------------------------------------------------
// Shared 128x128 SGEMM tile core. 256 threads, 8x8 per thread, BK=8.
// A is MxK row-major (pre-offset to tile row 0), lda given.
// TRANSB=false: B is KxN row-major (pre-offset to tile col 0).
// TRANSB=true : B is NxK row-major (pre-offset to tile row 0)  => C = A * B^T
// ---------------------------------------------------------------------------
template<bool TRANSB>
__device__ inline void sgemm_core(const float* __restrict__ A,
                                  const float* __restrict__ Bm,
                                  int lda, int ldb, int kChunks,
                                  float (&acc)[8][8])
{
    __shared__ float As[8][128];
    __shared__ float Bs[8][128];
    const int tid  = threadIdx.x;
    const int tx   = tid & 15, ty = tid >> 4;
    const int lrow = tid >> 1;          // 0..127
    const int lcol = (tid & 1) * 4;     // 0 or 4
    const int brow = tid >> 5;          // 0..7
    const int bcol = (tid & 31) * 4;    // 0..124
    for (int kb = 0; kb < kChunks; ++kb) {
        float4 av = *(const float4*)(A + (size_t)lrow * lda + (kb * 8 + lcol));
        As[lcol + 0][lrow] = av.x; As[lcol + 1][lrow] = av.y;
        As[lcol + 2][lrow] = av.z; As[lcol + 3][lrow] = av.w;
        if (TRANSB) {
            float4 bv = *(const float4*)(Bm + (size_t)lrow * ldb + (kb * 8 + lcol));
            Bs[lcol + 0][lrow] = bv.x; Bs[lcol + 1][lrow] = bv.y;
            Bs[lcol + 2][lrow] = bv.z; Bs[lcol + 3][lrow] = bv.w;
        } else {
            float4 bv = *(const float4*)(Bm + (size_t)(kb * 8 + brow) * ldb + bcol);
            *(float4*)&Bs[brow][bcol] = bv;
        }
        __syncthreads();
#pragma unroll
        for (int k = 0; k < 8; ++k) {
            float4 a0 = *(const float4*)&As[k][ty * 8];
            float4 a1 = *(const float4*)&As[k][ty * 8 + 4];
            float4 b0 = *(const float4*)&Bs[k][tx * 8];
            float4 b1 = *(const float4*)&Bs[k][tx * 8 + 4];
            float ar[8] = {a0.x, a0.y, a0.z, a0.w, a1.x, a1.y, a1.z, a1.w};
            float br[8] = {b0.x, b0.y, b0.z, b0.w, b1.x, b1.y, b1.z, b1.w};
#pragma unroll
            for (int i2 = 0; i2 < 8; ++i2)
#pragma unroll
                for (int j = 0; j < 8; ++j)
                    acc[i2][j] += ar[i2] * br[j];
        }
        __syncthreads();
    }
}

// ---------------------------------------------------------------------------
// 1x1 conv as GEMM: out[n] = W(128x128) @ X[n](128x4096) + bias
// grid (32, 16)
// ---------------------------------------------------------------------------
__global__ __launch_bounds__(256) void k_qkv(const float* __restrict__ X,
                                             const float* __restrict__ Wt,
                                             const float* __restrict__ bias,
                                             float* __restrict__ outp)
{
    const int n0  = blockIdx.x * 128;
    const int img = blockIdx.y;
    float acc[8][8] = {};
    sgemm_core<false>(Wt, X + (size_t)img * Dc * PIX + n0, Dc, PIX, Dc / 8, acc);
    const int tx = threadIdx.x & 15, ty = threadIdx.x >> 4;
    float* Cp = outp + (size_t)img * Dc * PIX + n0;
#pragma unroll
    for (int i2 = 0; i2 < 8; ++i2) {
        int mrow = ty * 8 + i2;
        float bv = bias[mrow];
        float4 v0 = make_float4(acc[i2][0] + bv, acc[i2][1] + bv, acc[i2][2] + bv, acc[i2][3] + bv);
        float4 v1 = make_float4(acc[i2][4] + bv, acc[i2][5] + bv, acc[i2][6] + bv, acc[i2][7] + bv);
        *(float4*)(Cp + (size_t)mrow * PIX + tx * 8)     = v0;
        *(float4*)(Cp + (size_t)mrow * PIX + tx * 8 + 4) = v1;
    }
}

// ---------------------------------------------------------------------------
// depthwise 3x3 (pad 1) add into v_all, incl. bvle. grid (16, 128, 16)
// ---------------------------------------------------------------------------
__global__ __launch_bounds__(256) void k_vdw(const float* __restrict__ X,
                                             const float* __restrict__ wvle,
                                             const float* __restrict__ bvle,
                                             float* __restrict__ v_all)
{
    const int n = blockIdx.z, c = blockIdx.y;
    const int p = blockIdx.x * 256 + threadIdx.x;
    const int y = p >> 6, x = p & 63;
    const float* xp = X + ((size_t)n * Dc + c) * PIX;
    const float* w  = wvle + c * 9;
    float s = bvle[c];
#pragma unroll
    for (int ky = 0; ky < 3; ++ky) {
        int yy = y + ky - 1;
        if (yy < 0 || yy >= 64) continue;
#pragma unroll
        for (int kx = 0; kx < 3; ++kx) {
            int xx = x + kx - 1;
            if (xx < 0 || xx >= 64) continue;
            s += w[ky * 3 + kx] * xp[yy * 64 + xx];
        }
    }
    v_all[((size_t)n * Dc + c) * PIX + p] += s;
}

// ---------------------------------------------------------------------------
// Fused depth path: relu(conv(dm,wd1,s2,p1)) -> relu(conv(.,wd2,s2,p1))
// d1 (134 MB) never hits HBM. grid (4,4,16), 16x16 output tile per block.
// ---------------------------------------------------------------------------
__global__ __launch_bounds__(256) void k_depth(const float* __restrict__ dm,
                                               const float* __restrict__ wd1,
                                               const float* __restrict__ bd1,
                                               const float* __restrict__ wd2,
                                               const float* __restrict__ bd2,
                                               float* __restrict__ dep)
{
    __shared__ float ds_[67 * 68];
    __shared__ float d1s[33 * 34];
    __shared__ float w1s[1152];
    __shared__ float w2s[1152];
    const int n   = blockIdx.z;
    const int oy0 = blockIdx.y * 16, ox0 = blockIdx.x * 16;
    const int tid = threadIdx.x;
    for (int idx = tid; idx < 1152; idx += 256) { w1s[idx] = wd1[idx]; w2s[idx] = wd2[idx]; }
    const int ry0 = 4 * oy0 - 3, rx0 = 4 * ox0 - 3;
    const float* dmp = dm + (size_t)n * 65536;
    for (int idx = tid; idx < 67 * 67; idx += 256) {
        int r = idx / 67, cc2 = idx % 67;
        int gy = ry0 + r, gx = rx0 + cc2;
        float v = 0.f;
        if (gy >= 0 && gy < 256 && gx >= 0 && gx < 256) v = dmp[gy * 256 + gx];
        ds_[r * 68 + cc2] = v;
    }
    __syncthreads();
    const int oy = tid >> 4, ox = tid & 15;
    const int Ybase = 2 * oy0 - 1, Xbase = 2 * ox0 - 1;
    float acc = 0.f;
    for (int c = 0; c < 128; ++c) {
        const float* w1 = &w1s[c * 9];
        const float  bc = bd1[c];
        for (int idx = tid; idx < 33 * 33; idx += 256) {
            int a = idx / 33, e = idx % 33;
            int Yg = Ybase + a, Xg = Xbase + e;
            float v = 0.f;
            if (Yg >= 0 && Yg < 128 && Xg >= 0 && Xg < 128) { // zero-pad of conv2, not conv of zeros
                float s = bc;
#pragma unroll
                for (int jy = 0; jy < 3; ++jy)
#pragma unroll
                    for (int jx = 0; jx < 3; ++jx)
                        s += w1[jy * 3 + jx] * ds_[(2 * a + jy) * 68 + (2 * e + jx)];
                v = fmaxf(s, 0.f);
            }
            d1s[a * 34 + e] = v;
        }
        __syncthreads();
        const float* w2 = &w2s[c * 9];
        float s2 = 0.f;
#pragma unroll
        for (int ky = 0; ky < 3; ++ky)
#pragma unroll
            for (int kx = 0; kx < 3; ++kx)
                s2 += w2[ky * 3 + kx] * d1s[(2 * oy + ky) * 34 + (2 * ox + kx)];
        acc += s2;
        __syncthreads();
    }
    dep[(size_t)n * PIX + (oy0 + oy) * 64 + (ox0 + ox)] = fmaxf(acc + bd2[0], 0.f);
}

// ---------------------------------------------------------------------------
// Per-token stats: key mask, sigmoid(dmin/dmed/dmax) of patch of _depth.
// Exact kth order statistic via stable counting (matches jnp.sort index).
// ---------------------------------------------------------------------------
__global__ void k_stats(const float* __restrict__ mI, const float* __restrict__ dep,
                        float* __restrict__ maskf, float* __restrict__ smed,
                        float* __restrict__ smaxA, float* __restrict__ sminA,
                        int ps, int outn, int L)
{
    int idx = blockIdx.x * 256 + threadIdx.x;
    if (idx >= Bb * L) return;
    int bi = idx / L, l = idx % L;
    int ti = l / (outn * outn); int rem = l % (outn * outn);
    int oh = rem / outn, ow = rem % outn;
    int n = bi * Tt + ti;
    const float* mp = mI + (size_t)n * PIX;
    const float* dp = dep + (size_t)n * PIX;
    int hw = ps * ps;
    float vals[64];
    float msum = 0.f;
    for (int py = 0; py < ps; ++py)
        for (int px = 0; px < ps; ++px) {
            int y = oh * ps + py, x = ow * ps + px;
            msum += mp[y * 64 + x];
            vals[py * ps + px] = dp[y * 64 + x];
        }
    float vmin = vals[0], vmax = vals[0];
    for (int a = 1; a < hw; ++a) { vmin = fminf(vmin, vals[a]); vmax = fmaxf(vmax, vals[a]); }
    int kk = (hw - 1) >> 1;
    float med = vals[0];
    for (int a = 0; a < hw; ++a) {
        int rank = 0;
        for (int b2 = 0; b2 < hw; ++b2)
            rank += (vals[b2] < vals[a]) || (vals[b2] == vals[a] && b2 < a);
        if (rank == kk) med = vals[a];
    }
    maskf[idx] = (msum / (float)hw > 0.5f) ? 1.f : 0.f;
    smed[idx]  = 1.f / (1.f + __expf(-med));
    smaxA[idx] = 1.f / (1.f + __expf(-vmax));
    sminA[idx] = 1.f / (1.f + __expf(-vmin));
}

// ---------------------------------------------------------------------------
// Patch-extract: dst[bi][l][f] = src[n][cbase+f/hw][oh*ps+py][ow*ps+px]
// float4 along f (px aligned to 4 for both patch sizes).
// ---------------------------------------------------------------------------
__global__ void k_patch(const float* __restrict__ src, float* __restrict__ dst,
                        int ps, int outn, int L, int F, int cbase)
{
    size_t idx = (size_t)blockIdx.x * 256 + threadIdx.x;
    size_t total = (size_t)Bb * L * F / 4;
    if (idx >= total) return;
    int f0 = (int)((idx * 4) % F);
    size_t t2 = (idx * 4) / F;
    int l = (int)(t2 % L);
    int bi = (int)(t2 / L);
    int hw = ps * ps;
    int ti = l / (outn * outn); int rem = l % (outn * outn);
    int oh = rem / outn, ow = rem % outn;
    int c = f0 / hw; int r = f0 % hw;
    int py = r / ps, px = r % ps;
    int n = bi * Tt + ti;
    float4 v = *(const float4*)(src + (((size_t)n * Dc + cbase + c) * 64 + oh * ps + py) * 64 + ow * ps + px);
    *(float4*)(dst + ((size_t)bi * L + l) * F + f0) = v;
}

// ---------------------------------------------------------------------------
// S = scale * Q @ K^T, optional K-split with fp32 atomics (S pre-zeroed).
// grid (L/128, L/128, B*ksplit)
// ---------------------------------------------------------------------------
__global__ __launch_bounds__(256) void k_qkT(const float* __restrict__ Qp,
                                             const float* __restrict__ Kp,
                                             float* __restrict__ S,
                                             int L, int F, int ksplit, float scale)
{
    const int bi = blockIdx.z / ksplit, ks = blockIdx.z % ksplit;
    const int kf = F / ksplit;
    const float* A  = Qp + (size_t)bi * L * F + (size_t)blockIdx.y * 128 * F + (size_t)ks * kf;
    const float* Bm = Kp + (size_t)bi * L * F + (size_t)blockIdx.x * 128 * F + (size_t)ks * kf;
    float acc[8][8] = {};
    sgemm_core<true>(A, Bm, F, F, kf / 8, acc);
    const int tx = threadIdx.x & 15, ty = threadIdx.x >> 4;
    float* Cp = S + (size_t)bi * L * L + (size_t)(blockIdx.y * 128 + ty * 8) * L + blockIdx.x * 128 + tx * 8;
    if (ksplit == 1) {
#pragma unroll
        for (int i2 = 0; i2 < 8; ++i2) {
            float4 v0 = make_float4(acc[i2][0] * scale, acc[i2][1] * scale, acc[i2][2] * scale, acc[i2][3] * scale);
            float4 v1 = make_float4(acc[i2][4] * scale, acc[i2][5] * scale, acc[i2][6] * scale, acc[i2][7] * scale);
            *(float4*)(Cp + (size_t)i2 * L)     = v0;
            *(float4*)(Cp + (size_t)i2 * L + 4) = v1;
        }
    } else {
#pragma unroll
        for (int i2 = 0; i2 < 8; ++i2)
#pragma unroll
            for (int j = 0; j < 8; ++j)
                atomicAdd(Cp + (size_t)i2 * L + j, acc[i2][j] * scale);
    }
}

// ---------------------------------------------------------------------------
// 3-head softmax over a row of S, combined prob written in place:
// P = (softmax(s*sig_med | mask) + softmax(s*sig_max) + softmax(s*sig_min))/3
// ---------------------------------------------------------------------------
__device__ inline float blockMax(float v, float* sh) {
#pragma unroll
    for (int o = 32; o > 0; o >>= 1) v = fmaxf(v, __shfl_down(v, o));
    __syncthreads();
    if ((threadIdx.x & 63) == 0) sh[threadIdx.x >> 6] = v;
    __syncthreads();
    return fmaxf(fmaxf(sh[0], sh[1]), fmaxf(sh[2], sh[3]));
}
__device__ inline float blockSum(float v, float* sh) {
#pragma unroll
    for (int o = 32; o > 0; o >>= 1) v += __shfl_down(v, o);
    __syncthreads();
    if ((threadIdx.x & 63) == 0) sh[threadIdx.x >> 6] = v;
    __syncthreads();
    return sh[0] + sh[1] + sh[2] + sh[3];
}

template<int NV>
__global__ __launch_bounds__(256) void k_softmax(float* __restrict__ S,
                                                 const float* __restrict__ maskf,
                                                 const float* __restrict__ smed,
                                                 const float* __restrict__ smaxA,
                                                 const float* __restrict__ sminA,
                                                 int L)
{
    __shared__ float sred[4];
    const int bi = blockIdx.y, q = blockIdx.x;
    float* row = S + (size_t)bi * L * L + (size_t)q * L;
    const float* mk  = maskf + bi * L;
    const float* s0p = smed  + bi * L;
    const float* s1p = smaxA + bi * L;
    const float* s2p = sminA + bi * L;
    const int tid = threadIdx.x;
    float a0[NV], a1[NV], a2[NV];
    float m0 = -3.4e38f, m1 = -3.4e38f, m2 = -3.4e38f;
#pragma unroll
    for (int e = 0; e < NV; ++e) {
        int k = e * 256 + tid;
        float sv = row[k];
        bool msk = mk[k] > 0.5f;
        float v0 = msk ? -1e9f : sv * s0p[k];
        float v1 = msk ? -1e9f : sv * s1p[k];
        float v2 = msk ? -1e9f : sv * s2p[k];
        a0[e] = v0; a1[e] = v1; a2[e] = v2;
        m0 = fmaxf(m0, v0); m1 = fmaxf(m1, v1); m2 = fmaxf(m2, v2);
    }
    m0 = blockMax(m0, sred); m1 = blockMax(m1, sred); m2 = blockMax(m2, sred);
    float l0 = 0.f, l1 = 0.f, l2 = 0.f;
#pragma unroll
    for (int e = 0; e < NV; ++e) {
        a0[e] = __expf(a0[e] - m0); l0 += a0[e];
        a1[e] = __expf(a1[e] - m1); l1 += a1[e];
        a2[e] = __expf(a2[e] - m2); l2 += a2[e];
    }
    l0 = blockSum(l0, sred); l1 = blockSum(l1, sred); l2 = blockSum(l2, sred);
    float c0 = 1.f / (3.f * l0), c1 = 1.f / (3.f * l1), c2 = 1.f / (3.f * l2);
#pragma unroll
    for (int e = 0; e < NV; ++e)
        row[e * 256 + tid] = a0[e] * c0 + a1[e] * c1 + a2[e] * c2;
}

// ---------------------------------------------------------------------------
// Y = P @ V, scatter-stored directly back to NCHW layout (un-patch fused).
// grid (F/128, L/128, B)
// ---------------------------------------------------------------------------
__global__ __launch_bounds__(256) void k_pv(const float* __restrict__ P,
                                            const float* __restrict__ Vp,
                                            float* __restrict__ catb,
                                            int L, int F, int ps, int outn, int cbase)
{
    const int bi = blockIdx.z;
    float acc[8][8] = {};
    sgemm_core<false>(P + (size_t)bi * L * L + (size_t)blockIdx.y * 128 * L,
                      Vp + (size_t)bi * L * F + blockIdx.x * 128, L, F, L / 8, acc);
    const int tx = threadIdx.x & 15, ty = threadIdx.x >> 4;
    const int hw = ps * ps;
#pragma unroll
    for (int i2 = 0; i2 < 8; ++i2) {
        int l = blockIdx.y * 128 + ty * 8 + i2;
        int ti = l / (outn * outn); int rem = l % (outn * outn);
        int oh = rem / outn, ow = rem % outn;
        int n = bi * Tt + ti;
#pragma unroll
        for (int j = 0; j < 8; ++j) {
            int f = blockIdx.x * 128 + tx * 8 + j;
            int c = cbase + f / hw; int r = f % hw;
            catb[(((size_t)n * Dc + c) * 64 + oh * ps + r / ps) * 64 + ow * ps + r % ps] = acc[i2][j];
        }
    }
}

// ---------------------------------------------------------------------------
// 3x3 conv (pad 1) 128->128 + bias + LeakyReLU(0.2). grid (16 tiles, 8 co-grp, 16 n)
// Weight reads are block-uniform -> scalar loads.
// ---------------------------------------------------------------------------
__global__ __launch_bounds__(256) void k_convout(const float* __restrict__ catb,
                                                 const float* __restrict__ wo,
                                                 const float* __restrict__ bo,
                                                 float* __restrict__ outp)
{
    __shared__ float xs[16 * 324];
    const int n = blockIdx.z;
    const int ty0 = (blockIdx.x >> 2) * 16, tx0 = (blockIdx.x & 3) * 16;
    const int cog = blockIdx.y;
    const int tid = threadIdx.x;
    const int py = tid >> 4, px = tid & 15;
    float acc[16] = {};
    for (int cc = 0; cc < 128; cc += 16) {
        __syncthreads();
        for (int idx = tid; idx < 16 * 324; idx += 256) {
            int ci = idx / 324; int rr = (idx % 324) / 18, c2 = (idx % 324) % 18;
            int gy = ty0 + rr - 1, gx = tx0 + c2 - 1;
            float v = 0.f;
            if (gy >= 0 && gy < 64 && gx >= 0 && gx < 64)
                v = catb[(((size_t)n * Dc + cc + ci) * 64 + gy) * 64 + gx];
            xs[idx] = v;
        }
        __syncthreads();
        for (int ci = 0; ci < 16; ++ci) {
#pragma unroll
            for (int kk = 0; kk < 9; ++kk) {
                float xv = xs[ci * 324 + (py + kk / 3) * 18 + px + kk % 3];
                const float* wp = wo + ((size_t)cog * 16 * Dc + (size_t)(cc + ci)) * 9 + kk;
#pragma unroll
                for (int j = 0; j < 16; ++j)
                    acc[j] += wp[(size_t)j * Dc * 9] * xv;  // block-uniform -> s_load
            }
        }
    }
#pragma unroll
    for (int j = 0; j < 16; ++j) {
        float v = acc[j] + bo[cog * 16 + j];
        v = (v >= 0.f) ? v : 0.2f * v;
        outp[(((size_t)n * Dc + cog * 16 + j) * 64 + ty0 + py) * 64 + tx0 + px] = v;
    }
}

// ---------------------------------------------------------------------------
extern "C" void kernel_launch(void* const* d_in, const int* in_sizes, int n_in,
                              void* d_out, int out_size, void* d_ws, size_t ws_size,
                              hipStream_t stream)
{
    (void)in_sizes; (void)n_in; (void)out_size; (void)ws_size;
    const float* x    = (const float*)d_in[0];
    const float* mI   = (const float*)d_in[1];
    const float* dmap = (const float*)d_in[2];
    const float* wq   = (const float*)d_in[3];
    const float* bq   = (const float*)d_in[4];
    const float* wk   = (const float*)d_in[5];
    const float* bk   = (const float*)d_in[6];
    const float* wv   = (const float*)d_in[7];
    const float* bv   = (const float*)d_in[8];
    const float* wvle = (const float*)d_in[9];
    const float* bvle = (const float*)d_in[10];
    const float* wd1  = (const float*)d_in[11];
    const float* bd1  = (const float*)d_in[12];
    const float* wd2  = (const float*)d_in[13];
    const float* bd2  = (const float*)d_in[14];
    const float* wo   = (const float*)d_in[15];
    const float* bo   = (const float*)d_in[16];

    // workspace layout (floats): needs ~218.4 MB total
    float* ws    = (float*)d_ws;
    float* q_all = ws;                    // 16*128*64*64
    float* k_all = q_all + 8388608;
    float* v_all = k_all + 8388608;
    float* catb  = v_all + 8388608;       // attention output, NCHW
    float* Qp    = catb + 8388608;        // patched Q (max 2*2048*1024)
    float* Kp    = Qp + 4194304;
    float* Vp    = Kp + 4194304;
    float* Sb    = Vp + 4194304;          // scores / probs (max 2*2048*2048)
    float* dep   = Sb + 8388608;          // _depth 16*64*64
    float* maskf = dep + 65536;
    float* smed  = maskf + 4096;
    float* smaxA = smed + 4096;
    float* sminA = smaxA + 4096;
    float* outp  = (float*)d_out;

    // output tuple part 2: depth_map passthrough
    hipMemcpyAsync(outp + 8388608, dmap, (size_t)16 * 65536 * sizeof(float),
                   hipMemcpyDeviceToDevice, stream);

    dim3 blk(256);
    k_qkv<<<dim3(32, 16), blk, 0, stream>>>(x, wq, bq, q_all);
    k_qkv<<<dim3(32, 16), blk, 0, stream>>>(x, wk, bk, k_all);
    k_qkv<<<dim3(32, 16), blk, 0, stream>>>(x, wv, bv, v_all);
    k_vdw<<<dim3(16, 128, 16), blk, 0, stream>>>(x, wvle, bvle, v_all);
    k_depth<<<dim3(4, 4, 16), blk, 0, stream>>>(dmap, wd1, bd1, wd2, bd2, dep);

    for (int i = 0; i < 2; ++i) {
        const int ps = (i == 0) ? 4 : 8;
        const int outn = 64 / ps;
        const int L = Tt * outn * outn;        // 2048 / 512
        const int F = 64 * ps * ps;            // 1024 / 4096
        const int cbase = i * 64;
        const float scale = 1.0f / sqrtf((float)F);

        k_stats<<<dim3((Bb * L + 255) / 256), blk, 0, stream>>>(mI, dep, maskf, smed, smaxA, sminA, ps, outn, L);
        const int pgrid = (int)(((size_t)Bb * L * F / 4 + 255) / 256);
        k_patch<<<dim3(pgrid), blk, 0, stream>>>(q_all, Qp, ps, outn, L, F, cbase);
        k_patch<<<dim3(pgrid), blk, 0, stream>>>(k_all, Kp, ps, outn, L, F, cbase);
        k_patch<<<dim3(pgrid), blk, 0, stream>>>(v_all, Vp, ps, outn, L, F, cbase);

        const int ksplit = (i == 0) ? 1 : 8;   // i=1 GEMM has only 32 tiles -> split K over 8
        if (ksplit > 1)
            hipMemsetAsync(Sb, 0, (size_t)Bb * L * L * sizeof(float), stream);
        k_qkT<<<dim3(L / 128, L / 128, Bb * ksplit), blk, 0, stream>>>(Qp, Kp, Sb, L, F, ksplit, scale);

        if (i == 0) k_softmax<8><<<dim3(L, Bb), blk, 0, stream>>>(Sb, maskf, smed, smaxA, sminA, L);
        else        k_softmax<2><<<dim3(L, Bb), blk, 0, stream>>>(Sb, maskf, smed, smaxA, sminA, L);

        k_pv<<<dim3(F / 128, L / 128, Bb), blk, 0, stream>>>(Sb, Vp, catb, L, F, ps, outn, cbase);
    }

    k_convout<<<dim3(16, 8, 16), blk, 0, stream>>>(catb, wo, bo, outp);
}

// Round 2
// 1007.501 us; speedup vs baseline: 2.3485x; 2.3485x over previous
//
#include <hip/hip_runtime.h>
#include <cmath>

typedef unsigned short u16;
typedef __attribute__((ext_vector_type(8))) __bf16 bf16x8;
typedef __attribute__((ext_vector_type(4))) float f32x4;

constexpr int Bb = 2, Tt = 8, Dc = 128, PIX = 4096; // b=2, c=128, 64x64 imgs

__device__ inline u16 f2bf(float f) {
    unsigned u = __builtin_bit_cast(unsigned, f);
    u += 0x7fffu + ((u >> 16) & 1u);
    return (u16)(u >> 16);
}
__device__ inline float bf2f(u16 h) {
    unsigned u = ((unsigned)h) << 16;
    return __builtin_bit_cast(float, u);
}

#define GLOAD16(gp, lp) __builtin_amdgcn_global_load_lds( \
    (const __attribute__((address_space(1))) void*)(const void*)(gp), \
    (__attribute__((address_space(3))) void*)(void*)(lp), 16, 0, 0)

// ---------------------------------------------------------------------------
// bf16 NT MFMA core: C(128x128) = A(128xK) * B(128xK)^T, tiles [row][k] in LDS.
// 256 thr = 4 waves; wave w owns 64x64 quadrant (wm=(w>>1)*64, wn=(w&1)*64).
// Verified layouts: A-frag A[m=lane&15][k=(lane>>4)*8+j]; C/D col=lane&15,
// row=(lane>>4)*4+reg.
// ---------------------------------------------------------------------------
__device__ inline void mfma_chunk(const u16* lAs, const u16* lBs, int wave, int lane,
                                  f32x4 (&acc)[4][4])
{
    const int wm = (wave >> 1) * 64, wn = (wave & 1) * 64;
    const int fr = lane & 15;
    const int kq = (lane >> 4) * 8;
    bf16x8 av[4], bv[4];
#pragma unroll
    for (int i = 0; i < 4; ++i) av[i] = *(const bf16x8*)&lAs[(wm + i * 16 + fr) * 32 + kq];
#pragma unroll
    for (int j = 0; j < 4; ++j) bv[j] = *(const bf16x8*)&lBs[(wn + j * 16 + fr) * 32 + kq];
#pragma unroll
    for (int i = 0; i < 4; ++i)
#pragma unroll
        for (int j = 0; j < 4; ++j)
            acc[i][j] = __builtin_amdgcn_mfma_f32_16x16x32_bf16(av[i], bv[j], acc[i][j], 0, 0, 0);
}

__device__ inline void mfma_nt(const u16* A, int ldkA, const u16* B, int ldkB,
                               int kChunks, int wave, int lane,
                               u16* lAs, u16* lBs, f32x4 (&acc)[4][4])
{
    const int r = lane >> 2;
    const int kq8 = (lane & 3) * 8;
    const u16* ga0 = A + (size_t)(wave * 32 + r) * ldkA + kq8;
    const u16* ga1 = ga0 + (size_t)16 * ldkA;
    const u16* gb0 = B + (size_t)(wave * 32 + r) * ldkB + kq8;
    const u16* gb1 = gb0 + (size_t)16 * ldkB;
    for (int kb = 0; kb < kChunks; ++kb) {
        __syncthreads();                       // WAR: prior chunk's ds_reads done
        GLOAD16(ga0 + kb * 32, lAs + wave * 1024);
        GLOAD16(ga1 + kb * 32, lAs + wave * 1024 + 512);
        GLOAD16(gb0 + kb * 32, lBs + wave * 1024);
        GLOAD16(gb1 + kb * 32, lBs + wave * 1024 + 512);
        __syncthreads();                       // drains vmcnt(0) before barrier
        mfma_chunk(lAs, lBs, wave, lane, acc);
    }
}

// ---------------------------------------------------------------------------
// Weight prep: Wqkv[3*128][128] bf16 stacked; WoT[tap][cout][cin] bf16.
// ---------------------------------------------------------------------------
__global__ void k_prep(const float* __restrict__ wq, const float* __restrict__ wk,
                       const float* __restrict__ wv, const float* __restrict__ wo,
                       u16* __restrict__ Wqkv, u16* __restrict__ WoT)
{
    int idx = blockIdx.x * 256 + threadIdx.x;
    if (idx < 49152) {
        const float* w = idx < 16384 ? wq : (idx < 32768 ? wk : wv);
        Wqkv[idx] = f2bf(w[idx & 16383]);
    }
    int j = idx - 49152;
    if (j >= 0 && j < 147456) {
        int tap = j / 16384, rem = j % 16384;  // rem = cout*128+cin
        WoT[j] = f2bf(wo[(size_t)rem * 9 + tap]);
    }
}

// ---------------------------------------------------------------------------
// Xt[n][pix][cin] bf16 from x[n][cin][pix] fp32 (LDS transpose, 64-pix tiles)
// ---------------------------------------------------------------------------
__global__ __launch_bounds__(256) void k_xt(const float* __restrict__ x, u16* __restrict__ Xt)
{
    __shared__ float ls[128 * 65];
    const int n = blockIdx.y, pix0 = blockIdx.x * 64;
#pragma unroll
    for (int rep = 0; rep < 32; ++rep) {
        int idx = rep * 256 + threadIdx.x;
        int cin = idx >> 6, p = idx & 63;
        ls[cin * 65 + p] = x[((size_t)n * Dc + cin) * PIX + pix0 + p];
    }
    __syncthreads();
#pragma unroll
    for (int rep = 0; rep < 32; ++rep) {
        int idx = rep * 256 + threadIdx.x;
        int p = idx >> 7, cin = idx & 127;
        Xt[((size_t)n * PIX + pix0 + p) * Dc + cin] = f2bf(ls[cin * 65 + p]);
    }
}

// ---------------------------------------------------------------------------
// Fused QKV: C[384][4096] = Wqkv * Xt^T per image; bf16 out + bias, routed.
// grid (32 pixtiles, 3 Mtiles, 16 imgs)
// ---------------------------------------------------------------------------
__global__ __launch_bounds__(256) void k_qkv_mfma(const u16* __restrict__ Wqkv,
                                                  const u16* __restrict__ Xt,
                                                  const float* __restrict__ bq,
                                                  const float* __restrict__ bk,
                                                  const float* __restrict__ bv,
                                                  u16* __restrict__ q_bf,
                                                  u16* __restrict__ k_bf,
                                                  u16* __restrict__ v_bf)
{
    __shared__ u16 lAs[4096], lBs[4096];
    const int tid = threadIdx.x, wave = tid >> 6, lane = tid & 63;
    const int mt = blockIdx.y, n = blockIdx.z, px0 = blockIdx.x * 128;
    f32x4 acc[4][4];
#pragma unroll
    for (int i = 0; i < 4; ++i)
#pragma unroll
        for (int j = 0; j < 4; ++j) acc[i][j] = (f32x4){0.f, 0.f, 0.f, 0.f};
    mfma_nt(Wqkv + (size_t)mt * 128 * 128, 128,
            Xt + ((size_t)n * PIX + px0) * 128, 128, 4, wave, lane, lAs, lBs, acc);
    const int wm = (wave >> 1) * 64, wn = (wave & 1) * 64;
    const int rb = (lane >> 4) * 4, cb = lane & 15;
#pragma unroll
    for (int i = 0; i < 4; ++i)
#pragma unroll
        for (int reg = 0; reg < 4; ++reg) {
            int gmg = mt * 128 + wm + i * 16 + rb + reg;     // stacked cout 0..383
            int sel = gmg >> 7, c = gmg & 127;
            float bias = (sel == 0 ? bq : sel == 1 ? bk : bv)[c];
            u16* dst = (sel == 0 ? q_bf : sel == 1 ? k_bf : v_bf);
#pragma unroll
            for (int j = 0; j < 4; ++j) {
                int pix = px0 + wn + j * 16 + cb;
                dst[((size_t)n * Dc + c) * PIX + pix] = f2bf(acc[i][j][reg] + bias);
            }
        }
}

// ---------------------------------------------------------------------------
// depthwise 3x3 add into bf16 v_all. grid (16, 128, 16)
// ---------------------------------------------------------------------------
__global__ __launch_bounds__(256) void k_vdw(const float* __restrict__ X,
                                             const float* __restrict__ wvle,
                                             const float* __restrict__ bvle,
                                             u16* __restrict__ v_bf)
{
    const int n = blockIdx.z, c = blockIdx.y;
    const int p = blockIdx.x * 256 + threadIdx.x;
    const int y = p >> 6, x = p & 63;
    const float* xp = X + ((size_t)n * Dc + c) * PIX;
    const float* w  = wvle + c * 9;
    float s = bvle[c];
#pragma unroll
    for (int ky = 0; ky < 3; ++ky) {
        int yy = y + ky - 1;
        if (yy < 0 || yy >= 64) continue;
#pragma unroll
        for (int kx = 0; kx < 3; ++kx) {
            int xx = x + kx - 1;
            if (xx < 0 || xx >= 64) continue;
            s += w[ky * 3 + kx] * xp[yy * 64 + xx];
        }
    }
    size_t idx = ((size_t)n * Dc + c) * PIX + p;
    v_bf[idx] = f2bf(bf2f(v_bf[idx]) + s);
}

// ---------------------------------------------------------------------------
// Fused depth path (unchanged, fp32): d1 never hits HBM. grid (4,4,16)
// ---------------------------------------------------------------------------
__global__ __launch_bounds__(256) void k_depth(const float* __restrict__ dm,
                                               const float* __restrict__ wd1,
                                               const float* __restrict__ bd1,
                                               const float* __restrict__ wd2,
                                               const float* __restrict__ bd2,
                                               float* __restrict__ dep)
{
    __shared__ float ds_[67 * 68];
    __shared__ float d1s[33 * 34];
    __shared__ float w1s[1152];
    __shared__ float w2s[1152];
    const int n   = blockIdx.z;
    const int oy0 = blockIdx.y * 16, ox0 = blockIdx.x * 16;
    const int tid = threadIdx.x;
    for (int idx = tid; idx < 1152; idx += 256) { w1s[idx] = wd1[idx]; w2s[idx] = wd2[idx]; }
    const int ry0 = 4 * oy0 - 3, rx0 = 4 * ox0 - 3;
    const float* dmp = dm + (size_t)n * 65536;
    for (int idx = tid; idx < 67 * 67; idx += 256) {
        int r = idx / 67, cc2 = idx % 67;
        int gy = ry0 + r, gx = rx0 + cc2;
        float v = 0.f;
        if (gy >= 0 && gy < 256 && gx >= 0 && gx < 256) v = dmp[gy * 256 + gx];
        ds_[r * 68 + cc2] = v;
    }
    __syncthreads();
    const int oy = tid >> 4, ox = tid & 15;
    const int Ybase = 2 * oy0 - 1, Xbase = 2 * ox0 - 1;
    float acc = 0.f;
    for (int c = 0; c < 128; ++c) {
        const float* w1 = &w1s[c * 9];
        const float  bc = bd1[c];
        for (int idx = tid; idx < 33 * 33; idx += 256) {
            int a = idx / 33, e = idx % 33;
            int Yg = Ybase + a, Xg = Xbase + e;
            float v = 0.f;
            if (Yg >= 0 && Yg < 128 && Xg >= 0 && Xg < 128) {
                float s = bc;
#pragma unroll
                for (int jy = 0; jy < 3; ++jy)
#pragma unroll
                    for (int jx = 0; jx < 3; ++jx)
                        s += w1[jy * 3 + jx] * ds_[(2 * a + jy) * 68 + (2 * e + jx)];
                v = fmaxf(s, 0.f);
            }
            d1s[a * 34 + e] = v;
        }
        __syncthreads();
        const float* w2 = &w2s[c * 9];
        float s2 = 0.f;
#pragma unroll
        for (int ky = 0; ky < 3; ++ky)
#pragma unroll
            for (int kx = 0; kx < 3; ++kx)
                s2 += w2[ky * 3 + kx] * d1s[(2 * oy + ky) * 34 + (2 * ox + kx)];
        acc += s2;
        __syncthreads();
    }
    dep[(size_t)n * PIX + (oy0 + oy) * 64 + (ox0 + ox)] = fmaxf(acc + bd2[0], 0.f);
}

// ---------------------------------------------------------------------------
// Per-token stats (unchanged, fp32)
// ---------------------------------------------------------------------------
__global__ void k_stats(const float* __restrict__ mI, const float* __restrict__ dep,
                        float* __restrict__ maskf, float* __restrict__ smed,
                        float* __restrict__ smaxA, float* __restrict__ sminA,
                        int ps, int outn, int L)
{
    int idx = blockIdx.x * 256 + threadIdx.x;
    if (idx >= Bb * L) return;
    int bi = idx / L, l = idx % L;
    int ti = l / (outn * outn); int rem = l % (outn * outn);
    int oh = rem / outn, ow = rem % outn;
    int n = bi * Tt + ti;
    const float* mp = mI + (size_t)n * PIX;
    const float* dp = dep + (size_t)n * PIX;
    int hw = ps * ps;
    float vals[64];
    float msum = 0.f;
    for (int py = 0; py < ps; ++py)
        for (int px = 0; px < ps; ++px) {
            int y = oh * ps + py, x = ow * ps + px;
            msum += mp[y * 64 + x];
            vals[py * ps + px] = dp[y * 64 + x];
        }
    float vmin = vals[0], vmax = vals[0];
    for (int a = 1; a < hw; ++a) { vmin = fminf(vmin, vals[a]); vmax = fmaxf(vmax, vals[a]); }
    int kk = (hw - 1) >> 1;
    float med = vals[0];
    for (int a = 0; a < hw; ++a) {
        int rank = 0;
        for (int b2 = 0; b2 < hw; ++b2)
            rank += (vals[b2] < vals[a]) || (vals[b2] == vals[a] && b2 < a);
        if (rank == kk) med = vals[a];
    }
    maskf[idx] = (msum / (float)hw > 0.5f) ? 1.f : 0.f;
    smed[idx]  = 1.f / (1.f + __expf(-med));
    smaxA[idx] = 1.f / (1.f + __expf(-vmax));
    sminA[idx] = 1.f / (1.f + __expf(-vmin));
}

// ---------------------------------------------------------------------------
// Patch-extract bf16 -> bf16 [bi][l][f], 4 elements (=4 px) per thread.
// ---------------------------------------------------------------------------
__global__ void k_patch_bf(const u16* __restrict__ src, u16* __restrict__ dst,
                           int ps, int outn, int L, int F, int cbase)
{
    size_t idx = (size_t)blockIdx.x * 256 + threadIdx.x;
    size_t total = (size_t)Bb * L * F / 4;
    if (idx >= total) return;
    int f0 = (int)((idx * 4) % F);
    size_t t2 = (idx * 4) / F;
    int l = (int)(t2 % L);
    int bi = (int)(t2 / L);
    int hw = ps * ps;
    int ti = l / (outn * outn); int rem = l % (outn * outn);
    int oh = rem / outn, ow = rem % outn;
    int c = f0 / hw, r = f0 % hw;
    int py = r / ps, px = r % ps;
    int n = bi * Tt + ti;
    size_t si = ((size_t)n * Dc + cbase + c) * PIX + (oh * ps + py) * 64 + ow * ps + px;
    *(uint2*)&dst[((size_t)bi * L + l) * F + f0] = *(const uint2*)&src[si];
}

// V transposed patch: Vt[bi][f][l] bf16. 4 consecutive l per thread.
__global__ void k_patchT(const u16* __restrict__ v_bf, u16* __restrict__ Vt,
                         int ps, int outn, int L, int F, int cbase)
{
    size_t idx = (size_t)blockIdx.x * 256 + threadIdx.x;
    size_t total = (size_t)Bb * F * L / 4;
    if (idx >= total) return;
    int l0 = (int)((idx * 4) % L);
    size_t t2 = (idx * 4) / L;
    int f = (int)(t2 % F);
    int bi = (int)(t2 / F);
    int hw = ps * ps;
    int c = cbase + f / hw, r = f % hw;
    int py = r / ps, px = r % ps;
    int ti = l0 / (outn * outn); int rem = l0 % (outn * outn);
    int oh = rem / outn, ow0 = rem % outn;
    size_t base = ((size_t)(bi * Tt + ti) * Dc + c) * PIX + (oh * ps + py) * 64 + px;
    u16 out4[4];
#pragma unroll
    for (int e = 0; e < 4; ++e) out4[e] = v_bf[base + (size_t)(ow0 + e) * ps];
    *(uint2*)&Vt[((size_t)bi * F + f) * L + l0] = *(uint2*)out4;
}

// ---------------------------------------------------------------------------
// S = scale * Q K^T (bf16 MFMA), fp32 out; split-K via atomics (S pre-zeroed).
// grid (L/128, L/128, Bb*ksplit)
// ---------------------------------------------------------------------------
__global__ __launch_bounds__(256) void k_qkT_mfma(const u16* __restrict__ Qp,
                                                  const u16* __restrict__ Kp,
                                                  float* __restrict__ S,
                                                  int L, int F, int ksplit, float scale)
{
    __shared__ u16 lAs[4096], lBs[4096];
    const int tid = threadIdx.x, wave = tid >> 6, lane = tid & 63;
    const int bi = blockIdx.z / ksplit, ks = blockIdx.z % ksplit;
    const int kf = F / ksplit;
    f32x4 acc[4][4];
#pragma unroll
    for (int i = 0; i < 4; ++i)
#pragma unroll
        for (int j = 0; j < 4; ++j) acc[i][j] = (f32x4){0.f, 0.f, 0.f, 0.f};
    mfma_nt(Qp + (size_t)bi * L * F + (size_t)blockIdx.y * 128 * F + (size_t)ks * kf, F,
            Kp + (size_t)bi * L * F + (size_t)blockIdx.x * 128 * F + (size_t)ks * kf, F,
            kf / 32, wave, lane, lAs, lBs, acc);
    const int wm = (wave >> 1) * 64, wn = (wave & 1) * 64;
    const int rb = (lane >> 4) * 4, cb = lane & 15;
    float* Cp = S + (size_t)bi * L * L;
#pragma unroll
    for (int i = 0; i < 4; ++i)
#pragma unroll
        for (int reg = 0; reg < 4; ++reg) {
            int gm = blockIdx.y * 128 + wm + i * 16 + rb + reg;
#pragma unroll
            for (int j = 0; j < 4; ++j) {
                int gn = blockIdx.x * 128 + wn + j * 16 + cb;
                float v = acc[i][j][reg] * scale;
                if (ksplit == 1) Cp[(size_t)gm * L + gn] = v;
                else             atomicAdd(&Cp[(size_t)gm * L + gn], v);
            }
        }
}

// ---------------------------------------------------------------------------
// 3-head softmax, combined probs written as bf16 into Pb.
// ---------------------------------------------------------------------------
__device__ inline float blockMax(float v, float* sh) {
#pragma unroll
    for (int o = 32; o > 0; o >>= 1) v = fmaxf(v, __shfl_down(v, o));
    __syncthreads();
    if ((threadIdx.x & 63) == 0) sh[threadIdx.x >> 6] = v;
    __syncthreads();
    return fmaxf(fmaxf(sh[0], sh[1]), fmaxf(sh[2], sh[3]));
}
__device__ inline float blockSum(float v, float* sh) {
#pragma unroll
    for (int o = 32; o > 0; o >>= 1) v += __shfl_down(v, o);
    __syncthreads();
    if ((threadIdx.x & 63) == 0) sh[threadIdx.x >> 6] = v;
    __syncthreads();
    return sh[0] + sh[1] + sh[2] + sh[3];
}

template<int NV>
__global__ __launch_bounds__(256) void k_softmax(const float* __restrict__ S,
                                                 u16* __restrict__ Pb,
                                                 const float* __restrict__ maskf,
                                                 const float* __restrict__ smed,
                                                 const float* __restrict__ smaxA,
                                                 const float* __restrict__ sminA,
                                                 int L)
{
    __shared__ float sred[4];
    const int bi = blockIdx.y, q = blockIdx.x;
    const float* row = S + (size_t)bi * L * L + (size_t)q * L;
    u16* prow = Pb + (size_t)bi * L * L + (size_t)q * L;
    const float* mk  = maskf + bi * L;
    const float* s0p = smed  + bi * L;
    const float* s1p = smaxA + bi * L;
    const float* s2p = sminA + bi * L;
    const int tid = threadIdx.x;
    float a0[NV], a1[NV], a2[NV];
    float m0 = -3.4e38f, m1 = -3.4e38f, m2 = -3.4e38f;
#pragma unroll
    for (int e = 0; e < NV; ++e) {
        int k = e * 256 + tid;
        float sv = row[k];
        bool msk = mk[k] > 0.5f;
        float v0 = msk ? -1e9f : sv * s0p[k];
        float v1 = msk ? -1e9f : sv * s1p[k];
        float v2 = msk ? -1e9f : sv * s2p[k];
        a0[e] = v0; a1[e] = v1; a2[e] = v2;
        m0 = fmaxf(m0, v0); m1 = fmaxf(m1, v1); m2 = fmaxf(m2, v2);
    }
    m0 = blockMax(m0, sred); m1 = blockMax(m1, sred); m2 = blockMax(m2, sred);
    float l0 = 0.f, l1 = 0.f, l2 = 0.f;
#pragma unroll
    for (int e = 0; e < NV; ++e) {
        a0[e] = __expf(a0[e] - m0); l0 += a0[e];
        a1[e] = __expf(a1[e] - m1); l1 += a1[e];
        a2[e] = __expf(a2[e] - m2); l2 += a2[e];
    }
    l0 = blockSum(l0, sred); l1 = blockSum(l1, sred); l2 = blockSum(l2, sred);
    float c0 = 1.f / (3.f * l0), c1 = 1.f / (3.f * l1), c2 = 1.f / (3.f * l2);
#pragma unroll
    for (int e = 0; e < NV; ++e)
        prow[e * 256 + tid] = f2bf(a0[e] * c0 + a1[e] * c1 + a2[e] * c2);
}

// ---------------------------------------------------------------------------
// Y = P @ V (bf16 MFMA, V stored [F][L]), scatter into catbT[pix][cin] bf16.
// grid (F/128, L/128, Bb)
// ---------------------------------------------------------------------------
__global__ __launch_bounds__(256) void k_pv_mfma(const u16* __restrict__ Pb,
                                                 const u16* __restrict__ Vt,
                                                 u16* __restrict__ catbT,
                                                 int L, int F, int ps, int outn, int cbase)
{
    __shared__ u16 lAs[4096], lBs[4096];
    const int tid = threadIdx.x, wave = tid >> 6, lane = tid & 63;
    const int bi = blockIdx.z;
    f32x4 acc[4][4];
#pragma unroll
    for (int i = 0; i < 4; ++i)
#pragma unroll
        for (int j = 0; j < 4; ++j) acc[i][j] = (f32x4){0.f, 0.f, 0.f, 0.f};
    mfma_nt(Pb + (size_t)bi * L * L + (size_t)blockIdx.y * 128 * L, L,
            Vt + (size_t)bi * F * L + (size_t)blockIdx.x * 128 * L, L,
            L / 32, wave, lane, lAs, lBs, acc);
    const int wm = (wave >> 1) * 64, wn = (wave & 1) * 64;
    const int rb = (lane >> 4) * 4, cb = lane & 15;
    const int hw = ps * ps;
#pragma unroll
    for (int i = 0; i < 4; ++i)
#pragma unroll
        for (int reg = 0; reg < 4; ++reg) {
            int l = blockIdx.y * 128 + wm + i * 16 + rb + reg;
            int ti = l / (outn * outn); int rem = l % (outn * outn);
            int oh = rem / outn, ow = rem % outn;
            int n = bi * Tt + ti;
#pragma unroll
            for (int j = 0; j < 4; ++j) {
                int f = blockIdx.x * 128 + wn + j * 16 + cb;
                int c = cbase + f / hw, r = f % hw;
                int pix = (oh * ps + r / ps) * 64 + ow * ps + r % ps;
                catbT[((size_t)n * PIX + pix) * Dc + c] = f2bf(acc[i][j][reg]);
            }
        }
}

// ---------------------------------------------------------------------------
// Output conv 3x3 as 9-tap implicit NT GEMM over catbT; OOB lanes read a
// zero page (per-lane global source is legal with global_load_lds).
// grid (512 pixel tiles)
// ---------------------------------------------------------------------------
__global__ __launch_bounds__(256) void k_conv_mfma(const u16* __restrict__ catbT,
                                                   const u16* __restrict__ WoT,
                                                   const float* __restrict__ bo,
                                                   const u16* __restrict__ zp,
                                                   float* __restrict__ outp)
{
    __shared__ u16 lAs[4096], lBs[4096];
    const int tid = threadIdx.x, wave = tid >> 6, lane = tid & 63;
    const int pix0 = blockIdx.x * 128;
    const int r = lane >> 2;
    const int kq8 = (lane & 3) * 8;
    f32x4 acc[4][4];
#pragma unroll
    for (int i = 0; i < 4; ++i)
#pragma unroll
        for (int j = 0; j < 4; ++j) acc[i][j] = (f32x4){0.f, 0.f, 0.f, 0.f};
    for (int tap = 0; tap < 9; ++tap) {
        const int dy = tap / 3 - 1, dx = tap % 3 - 1;
        const u16* ga[2];
#pragma unroll
        for (int s = 0; s < 2; ++s) {
            int pg = pix0 + wave * 32 + r + s * 16;
            int n = pg >> 12, p = pg & 4095;
            int y = (p >> 6) + dy, xx = (p & 63) + dx;
            bool ok = (y >= 0 && y < 64 && xx >= 0 && xx < 64);
            ga[s] = ok ? catbT + ((size_t)(n << 12) + y * 64 + xx) * Dc + kq8 : zp;
        }
        const u16* gb = WoT + tap * 16384 + (size_t)(wave * 32 + r) * 128 + kq8;
        for (int kc = 0; kc < 4; ++kc) {
            __syncthreads();
            GLOAD16(ga[0] + kc * 32, lAs + wave * 1024);
            GLOAD16(ga[1] + kc * 32, lAs + wave * 1024 + 512);
            GLOAD16(gb + kc * 32, lBs + wave * 1024);
            GLOAD16(gb + 2048 + kc * 32, lBs + wave * 1024 + 512);
            __syncthreads();
            mfma_chunk(lAs, lBs, wave, lane, acc);
        }
    }
    const int wm = (wave >> 1) * 64, wn = (wave & 1) * 64;
    const int rb = (lane >> 4) * 4, cb = lane & 15;
#pragma unroll
    for (int i = 0; i < 4; ++i)
#pragma unroll
        for (int reg = 0; reg < 4; ++reg) {
            int pg = pix0 + wm + i * 16 + rb + reg;
            int n = pg >> 12, p = pg & 4095;
#pragma unroll
            for (int j = 0; j < 4; ++j) {
                int cout = wn + j * 16 + cb;
                float v = acc[i][j][reg] + bo[cout];
                v = (v >= 0.f) ? v : 0.2f * v;
                outp[((size_t)n * Dc + cout) * PIX + p] = v;
            }
        }
}

// ---------------------------------------------------------------------------
extern "C" void kernel_launch(void* const* d_in, const int* in_sizes, int n_in,
                              void* d_out, int out_size, void* d_ws, size_t ws_size,
                              hipStream_t stream)
{
    (void)in_sizes; (void)n_in; (void)out_size; (void)ws_size;
    const float* x    = (const float*)d_in[0];
    const float* mI   = (const float*)d_in[1];
    const float* dmap = (const float*)d_in[2];
    const float* wq   = (const float*)d_in[3];
    const float* bq   = (const float*)d_in[4];
    const float* wk   = (const float*)d_in[5];
    const float* bk   = (const float*)d_in[6];
    const float* wv   = (const float*)d_in[7];
    const float* bv   = (const float*)d_in[8];
    const float* wvle = (const float*)d_in[9];
    const float* bvle = (const float*)d_in[10];
    const float* wd1  = (const float*)d_in[11];
    const float* bd1  = (const float*)d_in[12];
    const float* wd2  = (const float*)d_in[13];
    const float* bd2  = (const float*)d_in[14];
    const float* wo   = (const float*)d_in[15];
    const float* bo   = (const float*)d_in[16];

    // workspace layout (~160 MB)
    char* w8 = (char*)d_ws;
    u16*   q_bf  = (u16*)(w8);                    // 16 MB each
    u16*   k_bf  = (u16*)(w8 + 0x1000000);
    u16*   v_bf  = (u16*)(w8 + 0x2000000);
    u16*   Xt    = (u16*)(w8 + 0x3000000);
    u16*   catbT = (u16*)(w8 + 0x4000000);
    u16*   Qp    = (u16*)(w8 + 0x5000000);        // 8 MB each
    u16*   Kp    = (u16*)(w8 + 0x5800000);
    u16*   Vt    = (u16*)(w8 + 0x6000000);
    float* Sb    = (float*)(w8 + 0x6800000);      // 32 MB
    u16*   Pb    = (u16*)(w8 + 0x8800000);        // 16 MB
    float* dep   = (float*)(w8 + 0x9800000);
    float* maskf = (float*)(w8 + 0x9840000);
    float* smed  = (float*)(w8 + 0x9844000);
    float* smaxA = (float*)(w8 + 0x9848000);
    float* sminA = (float*)(w8 + 0x984C000);
    u16*   Wqkv  = (u16*)(w8 + 0x9850000);
    u16*   WoT   = (u16*)(w8 + 0x9868000);
    u16*   zp    = (u16*)(w8 + 0x98B0000);
    float* outp  = (float*)d_out;

    hipMemcpyAsync(outp + 8388608, dmap, (size_t)16 * 65536 * sizeof(float),
                   hipMemcpyDeviceToDevice, stream);
    hipMemsetAsync(zp, 0, 256, stream);

    dim3 blk(256);
    k_prep<<<dim3(768), blk, 0, stream>>>(wq, wk, wv, wo, Wqkv, WoT);
    k_xt<<<dim3(64, 16), blk, 0, stream>>>(x, Xt);
    k_qkv_mfma<<<dim3(32, 3, 16), blk, 0, stream>>>(Wqkv, Xt, bq, bk, bv, q_bf, k_bf, v_bf);
    k_vdw<<<dim3(16, 128, 16), blk, 0, stream>>>(x, wvle, bvle, v_bf);
    k_depth<<<dim3(4, 4, 16), blk, 0, stream>>>(dmap, wd1, bd1, wd2, bd2, dep);

    for (int i = 0; i < 2; ++i) {
        const int ps = (i == 0) ? 4 : 8;
        const int outn = 64 / ps;
        const int L = Tt * outn * outn;        // 2048 / 512
        const int F = 64 * ps * ps;            // 1024 / 4096
        const int cbase = i * 64;
        const float scale = 1.0f / sqrtf((float)F);
        const int ksplit = (i == 0) ? 1 : 8;

        k_stats<<<dim3((Bb * L + 255) / 256), blk, 0, stream>>>(mI, dep, maskf, smed, smaxA, sminA, ps, outn, L);
        const int pgrid = (int)(((size_t)Bb * L * F / 4 + 255) / 256);
        k_patch_bf<<<dim3(pgrid), blk, 0, stream>>>(q_bf, Qp, ps, outn, L, F, cbase);
        k_patch_bf<<<dim3(pgrid), blk, 0, stream>>>(k_bf, Kp, ps, outn, L, F, cbase);
        k_patchT<<<dim3(pgrid), blk, 0, stream>>>(v_bf, Vt, ps, outn, L, F, cbase);

        if (ksplit > 1)
            hipMemsetAsync(Sb, 0, (size_t)Bb * L * L * sizeof(float), stream);
        k_qkT_mfma<<<dim3(L / 128, L / 128, Bb * ksplit), blk, 0, stream>>>(Qp, Kp, Sb, L, F, ksplit, scale);

        if (i == 0) k_softmax<8><<<dim3(L, Bb), blk, 0, stream>>>(Sb, Pb, maskf, smed, smaxA, sminA, L);
        else        k_softmax<2><<<dim3(L, Bb), blk, 0, stream>>>(Sb, Pb, maskf, smed, smaxA, sminA, L);

        k_pv_mfma<<<dim3(F / 128, L / 128, Bb), blk, 0, stream>>>(Pb, Vt, catbT, L, F, ps, outn, cbase);
    }

    k_conv_mfma<<<dim3(512), blk, 0, stream>>>(catbT, WoT, bo, zp, outp);
}

// Round 3
// 653.595 us; speedup vs baseline: 3.6201x; 1.5415x over previous
//
#include <hip/hip_runtime.h>
#include <cmath>

typedef unsigned short u16;
typedef __attribute__((ext_vector_type(8))) __bf16 bf16x8;
typedef __attribute__((ext_vector_type(4))) float f32x4;

constexpr int Bb = 2, Tt = 8, Dc = 128, PIX = 4096; // b=2, c=128, 64x64 imgs

__device__ inline u16 f2bf(float f) {
    unsigned u = __builtin_bit_cast(unsigned, f);
    u += 0x7fffu + ((u >> 16) & 1u);
    return (u16)(u >> 16);
}
__device__ inline float bf2f(u16 h) {
    unsigned u = ((unsigned)h) << 16;
    return __builtin_bit_cast(float, u);
}

#define GLOAD16(gp, lp) __builtin_amdgcn_global_load_lds( \
    (const __attribute__((address_space(1))) void*)(const void*)(gp), \
    (__attribute__((address_space(3))) void*)(void*)(lp), 16, 0, 0)

// ---------------------------------------------------------------------------
// bf16 NT MFMA core: C(128x128) = A(128xK) * B(128xK)^T.
// LDS layout [row][kseg] with XOR swizzle: stored seg c holds global seg
// c ^ ((row>>1)&3)  -> each 16-lane ds_read phase spreads over all 32 banks
// (bank base = (row&1)*16 + c*4; swizzle makes c take all 4 values per parity).
// global_load_lds dest is lane*16B (wave-uniform base), so the swizzle is
// implemented by permuting each lane's GLOBAL source k-segment.
// ---------------------------------------------------------------------------
__device__ inline void mfma_chunk(const u16* lAs, const u16* lBs, int wave, int lane,
                                  f32x4 (&acc)[4][4])
{
    const int wm = (wave >> 1) * 64, wn = (wave & 1) * 64;
    const int fr = lane & 15;
    const int q4 = lane >> 4;                         // wanted global k-quarter
    const int sw = (q4 ^ ((fr >> 1) & 3)) * 8;        // swizzled storage seg
    bf16x8 av[4], bv[4];
#pragma unroll
    for (int i = 0; i < 4; ++i) av[i] = *(const bf16x8*)&lAs[(wm + i * 16 + fr) * 32 + sw];
#pragma unroll
    for (int j = 0; j < 4; ++j) bv[j] = *(const bf16x8*)&lBs[(wn + j * 16 + fr) * 32 + sw];
#pragma unroll
    for (int i = 0; i < 4; ++i)
#pragma unroll
        for (int j = 0; j < 4; ++j)
            acc[i][j] = __builtin_amdgcn_mfma_f32_16x16x32_bf16(av[i], bv[j], acc[i][j], 0, 0, 0);
}

__device__ inline void mfma_nt(const u16* A, int ldkA, const u16* B, int ldkB,
                               int kChunks, int wave, int lane,
                               u16* lAs, u16* lBs, f32x4 (&acc)[4][4])
{
    const int r = lane >> 2;                              // row within 16-group
    const int kq8 = ((lane & 3) ^ ((r >> 1) & 3)) * 8;    // swizzled source seg
    const u16* ga0 = A + (size_t)(wave * 32 + r) * ldkA + kq8;
    const u16* ga1 = ga0 + (size_t)16 * ldkA;             // (r+16)>>1 &3 == r>>1 &3
    const u16* gb0 = B + (size_t)(wave * 32 + r) * ldkB + kq8;
    const u16* gb1 = gb0 + (size_t)16 * ldkB;
    for (int kb = 0; kb < kChunks; ++kb) {
        __syncthreads();                       // WAR: prior chunk's ds_reads done
        GLOAD16(ga0 + kb * 32, lAs + wave * 1024);
        GLOAD16(ga1 + kb * 32, lAs + wave * 1024 + 512);
        GLOAD16(gb0 + kb * 32, lBs + wave * 1024);
        GLOAD16(gb1 + kb * 32, lBs + wave * 1024 + 512);
        __syncthreads();                       // drains vmcnt(0) before barrier
        mfma_chunk(lAs, lBs, wave, lane, acc);
    }
}

// ---------------------------------------------------------------------------
// Weight prep: Wqkv[3*128][128] bf16 stacked; WoT[tap][cout][cin] bf16.
// ---------------------------------------------------------------------------
__global__ void k_prep(const float* __restrict__ wq, const float* __restrict__ wk,
                       const float* __restrict__ wv, const float* __restrict__ wo,
                       u16* __restrict__ Wqkv, u16* __restrict__ WoT)
{
    int idx = blockIdx.x * 256 + threadIdx.x;
    if (idx < 49152) {
        const float* w = idx < 16384 ? wq : (idx < 32768 ? wk : wv);
        Wqkv[idx] = f2bf(w[idx & 16383]);
    }
    int j = idx - 49152;
    if (j >= 0 && j < 147456) {
        int tap = j / 16384, rem = j % 16384;  // rem = cout*128+cin
        WoT[j] = f2bf(wo[(size_t)rem * 9 + tap]);
    }
}

// ---------------------------------------------------------------------------
// Xt[n][pix][cin] bf16 from x[n][cin][pix] fp32 (LDS transpose, 64-pix tiles)
// ---------------------------------------------------------------------------
__global__ __launch_bounds__(256) void k_xt(const float* __restrict__ x, u16* __restrict__ Xt)
{
    __shared__ float ls[128 * 65];
    const int n = blockIdx.y, pix0 = blockIdx.x * 64;
#pragma unroll
    for (int rep = 0; rep < 32; ++rep) {
        int idx = rep * 256 + threadIdx.x;
        int cin = idx >> 6, p = idx & 63;
        ls[cin * 65 + p] = x[((size_t)n * Dc + cin) * PIX + pix0 + p];
    }
    __syncthreads();
#pragma unroll
    for (int rep = 0; rep < 32; ++rep) {
        int idx = rep * 256 + threadIdx.x;
        int p = idx >> 7, cin = idx & 127;
        Xt[((size_t)n * PIX + pix0 + p) * Dc + cin] = f2bf(ls[cin * 65 + p]);
    }
}

// ---------------------------------------------------------------------------
// Fused QKV: C[384][4096] = Wqkv * Xt^T per image; bf16 out + bias, routed.
// grid (32 pixtiles, 3 Mtiles, 16 imgs)
// ---------------------------------------------------------------------------
__global__ __launch_bounds__(256) void k_qkv_mfma(const u16* __restrict__ Wqkv,
                                                  const u16* __restrict__ Xt,
                                                  const float* __restrict__ bq,
                                                  const float* __restrict__ bk,
                                                  const float* __restrict__ bv,
                                                  u16* __restrict__ q_bf,
                                                  u16* __restrict__ k_bf,
                                                  u16* __restrict__ v_bf)
{
    __shared__ u16 lAs[4096], lBs[4096];
    const int tid = threadIdx.x, wave = tid >> 6, lane = tid & 63;
    const int mt = blockIdx.y, n = blockIdx.z, px0 = blockIdx.x * 128;
    f32x4 acc[4][4];
#pragma unroll
    for (int i = 0; i < 4; ++i)
#pragma unroll
        for (int j = 0; j < 4; ++j) acc[i][j] = (f32x4){0.f, 0.f, 0.f, 0.f};
    mfma_nt(Wqkv + (size_t)mt * 128 * 128, 128,
            Xt + ((size_t)n * PIX + px0) * 128, 128, 4, wave, lane, lAs, lBs, acc);
    const int wm = (wave >> 1) * 64, wn = (wave & 1) * 64;
    const int rb = (lane >> 4) * 4, cb = lane & 15;
#pragma unroll
    for (int i = 0; i < 4; ++i)
#pragma unroll
        for (int reg = 0; reg < 4; ++reg) {
            int gmg = mt * 128 + wm + i * 16 + rb + reg;     // stacked cout 0..383
            int sel = gmg >> 7, c = gmg & 127;
            float bias = (sel == 0 ? bq : sel == 1 ? bk : bv)[c];
            u16* dst = (sel == 0 ? q_bf : sel == 1 ? k_bf : v_bf);
#pragma unroll
            for (int j = 0; j < 4; ++j) {
                int pix = px0 + wn + j * 16 + cb;
                dst[((size_t)n * Dc + c) * PIX + pix] = f2bf(acc[i][j][reg] + bias);
            }
        }
}

// ---------------------------------------------------------------------------
// depthwise 3x3 add into bf16 v_all. grid (16, 128, 16)
// ---------------------------------------------------------------------------
__global__ __launch_bounds__(256) void k_vdw(const float* __restrict__ X,
                                             const float* __restrict__ wvle,
                                             const float* __restrict__ bvle,
                                             u16* __restrict__ v_bf)
{
    const int n = blockIdx.z, c = blockIdx.y;
    const int p = blockIdx.x * 256 + threadIdx.x;
    const int y = p >> 6, x = p & 63;
    const float* xp = X + ((size_t)n * Dc + c) * PIX;
    const float* w  = wvle + c * 9;
    float s = bvle[c];
#pragma unroll
    for (int ky = 0; ky < 3; ++ky) {
        int yy = y + ky - 1;
        if (yy < 0 || yy >= 64) continue;
#pragma unroll
        for (int kx = 0; kx < 3; ++kx) {
            int xx = x + kx - 1;
            if (xx < 0 || xx >= 64) continue;
            s += w[ky * 3 + kx] * xp[yy * 64 + xx];
        }
    }
    size_t idx = ((size_t)n * Dc + c) * PIX + p;
    v_bf[idx] = f2bf(bf2f(v_bf[idx]) + s);
}

// ---------------------------------------------------------------------------
// Fused depth path (fp32): d1 never hits HBM. grid (4,4,16)
// ---------------------------------------------------------------------------
__global__ __launch_bounds__(256) void k_depth(const float* __restrict__ dm,
                                               const float* __restrict__ wd1,
                                               const float* __restrict__ bd1,
                                               const float* __restrict__ wd2,
                                               const float* __restrict__ bd2,
                                               float* __restrict__ dep)
{
    __shared__ float ds_[67 * 68];
    __shared__ float d1s[33 * 34];
    __shared__ float w1s[1152];
    __shared__ float w2s[1152];
    const int n   = blockIdx.z;
    const int oy0 = blockIdx.y * 16, ox0 = blockIdx.x * 16;
    const int tid = threadIdx.x;
    for (int idx = tid; idx < 1152; idx += 256) { w1s[idx] = wd1[idx]; w2s[idx] = wd2[idx]; }
    const int ry0 = 4 * oy0 - 3, rx0 = 4 * ox0 - 3;
    const float* dmp = dm + (size_t)n * 65536;
    for (int idx = tid; idx < 67 * 67; idx += 256) {
        int r = idx / 67, cc2 = idx % 67;
        int gy = ry0 + r, gx = rx0 + cc2;
        float v = 0.f;
        if (gy >= 0 && gy < 256 && gx >= 0 && gx < 256) v = dmp[gy * 256 + gx];
        ds_[r * 68 + cc2] = v;
    }
    __syncthreads();
    const int oy = tid >> 4, ox = tid & 15;
    const int Ybase = 2 * oy0 - 1, Xbase = 2 * ox0 - 1;
    float acc = 0.f;
    for (int c = 0; c < 128; ++c) {
        const float* w1 = &w1s[c * 9];
        const float  bc = bd1[c];
        for (int idx = tid; idx < 33 * 33; idx += 256) {
            int a = idx / 33, e = idx % 33;
            int Yg = Ybase + a, Xg = Xbase + e;
            float v = 0.f;
            if (Yg >= 0 && Yg < 128 && Xg >= 0 && Xg < 128) {
                float s = bc;
#pragma unroll
                for (int jy = 0; jy < 3; ++jy)
#pragma unroll
                    for (int jx = 0; jx < 3; ++jx)
                        s += w1[jy * 3 + jx] * ds_[(2 * a + jy) * 68 + (2 * e + jx)];
                v = fmaxf(s, 0.f);
            }
            d1s[a * 34 + e] = v;
        }
        __syncthreads();
        const float* w2 = &w2s[c * 9];
        float s2 = 0.f;
#pragma unroll
        for (int ky = 0; ky < 3; ++ky)
#pragma unroll
            for (int kx = 0; kx < 3; ++kx)
                s2 += w2[ky * 3 + kx] * d1s[(2 * oy + ky) * 34 + (2 * ox + kx)];
        acc += s2;
        __syncthreads();
    }
    dep[(size_t)n * PIX + (oy0 + oy) * 64 + (ox0 + ox)] = fmaxf(acc + bd2[0], 0.f);
}

// ---------------------------------------------------------------------------
// Wave-parallel per-token stats: one patch element per lane; min/max/mask via
// shfl_xor butterfly in aligned HW-lane groups; median = lane whose stable
// rank straddles kk (ties share the same VALUE, so any tied lane is exact).
// grid: 256 blocks for both scales (was 4 blocks + O(hw^2) serial -> 323 us).
// ---------------------------------------------------------------------------
template<int PS>
__global__ __launch_bounds__(256) void k_stats2(const float* __restrict__ mI,
                                                const float* __restrict__ dep,
                                                float* __restrict__ maskf,
                                                float* __restrict__ smed,
                                                float* __restrict__ smaxA,
                                                float* __restrict__ sminA,
                                                int outn, int L)
{
    constexpr int HW = PS * PS;              // 16 or 64
    constexpr int TPB = 256 / HW;            // tokens per block
    const int tok = blockIdx.x * TPB + threadIdx.x / HW;
    const int el  = threadIdx.x % HW;
    if (tok >= Bb * L) return;
    const int bi = tok / L, l = tok % L;
    const int ti = l / (outn * outn); const int rem = l % (outn * outn);
    const int oh = rem / outn, ow = rem % outn;
    const int n = bi * Tt + ti;
    const int py = el / PS, px = el % PS;
    const size_t off = (size_t)n * PIX + (size_t)(oh * PS + py) * 64 + ow * PS + px;
    const float mv = mI[off];
    const float dv = dep[off];
    float msum = mv, vmin = dv, vmax = dv;
#pragma unroll
    for (int o = HW / 2; o > 0; o >>= 1) {
        msum += __shfl_xor(msum, o);
        vmin = fminf(vmin, __shfl_xor(vmin, o));
        vmax = fmaxf(vmax, __shfl_xor(vmax, o));
    }
    const int gbase = (threadIdx.x & 63) & ~(HW - 1);   // group base lane in wave
    int cl = 0, ce = 0;
#pragma unroll
    for (int b2 = 0; b2 < HW; ++b2) {
        float vb = __shfl(dv, gbase + b2);
        cl += (vb < dv);
        ce += (vb == dv);
    }
    constexpr int kk = (HW - 1) / 2;
    if (el == 0) {
        maskf[tok] = (msum / (float)HW > 0.5f) ? 1.f : 0.f;
        smaxA[tok] = 1.f / (1.f + __expf(-vmax));
        sminA[tok] = 1.f / (1.f + __expf(-vmin));
    }
    if (cl <= kk && kk < cl + ce)
        smed[tok] = 1.f / (1.f + __expf(-dv));
}

// ---------------------------------------------------------------------------
// Patch-extract bf16 -> bf16 [bi][l][f], 4 elements (=4 px) per thread.
// ---------------------------------------------------------------------------
__global__ void k_patch_bf(const u16* __restrict__ src, u16* __restrict__ dst,
                           int ps, int outn, int L, int F, int cbase)
{
    size_t idx = (size_t)blockIdx.x * 256 + threadIdx.x;
    size_t total = (size_t)Bb * L * F / 4;
    if (idx >= total) return;
    int f0 = (int)((idx * 4) % F);
    size_t t2 = (idx * 4) / F;
    int l = (int)(t2 % L);
    int bi = (int)(t2 / L);
    int hw = ps * ps;
    int ti = l / (outn * outn); int rem = l % (outn * outn);
    int oh = rem / outn, ow = rem % outn;
    int c = f0 / hw, r = f0 % hw;
    int py = r / ps, px = r % ps;
    int n = bi * Tt + ti;
    size_t si = ((size_t)n * Dc + cbase + c) * PIX + (oh * ps + py) * 64 + ow * ps + px;
    *(uint2*)&dst[((size_t)bi * L + l) * F + f0] = *(const uint2*)&src[si];
}

// V transposed patch: Vt[bi][f][l] bf16. 4 consecutive l per thread.
__global__ void k_patchT(const u16* __restrict__ v_bf, u16* __restrict__ Vt,
                         int ps, int outn, int L, int F, int cbase)
{
    size_t idx = (size_t)blockIdx.x * 256 + threadIdx.x;
    size_t total = (size_t)Bb * F * L / 4;
    if (idx >= total) return;
    int l0 = (int)((idx * 4) % L);
    size_t t2 = (idx * 4) / L;
    int f = (int)(t2 % F);
    int bi = (int)(t2 / F);
    int hw = ps * ps;
    int c = cbase + f / hw, r = f % hw;
    int py = r / ps, px = r % ps;
    int ti = l0 / (outn * outn); int rem = l0 % (outn * outn);
    int oh = rem / outn, ow0 = rem % outn;
    size_t base = ((size_t)(bi * Tt + ti) * Dc + c) * PIX + (oh * ps + py) * 64 + px;
    u16 out4[4];
#pragma unroll
    for (int e = 0; e < 4; ++e) out4[e] = v_bf[base + (size_t)(ow0 + e) * ps];
    *(uint2*)&Vt[((size_t)bi * F + f) * L + l0] = *(uint2*)out4;
}

// ---------------------------------------------------------------------------
// S = scale * Q K^T (bf16 MFMA), fp32 out. Split-K writes to DISJOINT partial
// buffers (S + ks*Bb*L*L) -- no atomics; softmax sums the partials.
// grid (L/128, L/128, Bb*ksplit)
// ---------------------------------------------------------------------------
__global__ __launch_bounds__(256) void k_qkT_mfma(const u16* __restrict__ Qp,
                                                  const u16* __restrict__ Kp,
                                                  float* __restrict__ S,
                                                  int L, int F, int ksplit, float scale)
{
    __shared__ u16 lAs[4096], lBs[4096];
    const int tid = threadIdx.x, wave = tid >> 6, lane = tid & 63;
    const int bi = blockIdx.z / ksplit, ks = blockIdx.z % ksplit;
    const int kf = F / ksplit;
    f32x4 acc[4][4];
#pragma unroll
    for (int i = 0; i < 4; ++i)
#pragma unroll
        for (int j = 0; j < 4; ++j) acc[i][j] = (f32x4){0.f, 0.f, 0.f, 0.f};
    mfma_nt(Qp + (size_t)bi * L * F + (size_t)blockIdx.y * 128 * F + (size_t)ks * kf, F,
            Kp + (size_t)bi * L * F + (size_t)blockIdx.x * 128 * F + (size_t)ks * kf, F,
            kf / 32, wave, lane, lAs, lBs, acc);
    const int wm = (wave >> 1) * 64, wn = (wave & 1) * 64;
    const int rb = (lane >> 4) * 4, cb = lane & 15;
    float* Cp = S + ((size_t)ks * Bb + bi) * L * L;
#pragma unroll
    for (int i = 0; i < 4; ++i)
#pragma unroll
        for (int reg = 0; reg < 4; ++reg) {
            int gm = blockIdx.y * 128 + wm + i * 16 + rb + reg;
#pragma unroll
            for (int j = 0; j < 4; ++j) {
                int gn = blockIdx.x * 128 + wn + j * 16 + cb;
                Cp[(size_t)gm * L + gn] = acc[i][j][reg] * scale;
            }
        }
}

// ---------------------------------------------------------------------------
// 3-head softmax (sums NSPLIT partial S buffers), combined probs -> bf16 Pb.
// ---------------------------------------------------------------------------
__device__ inline float blockMax(float v, float* sh) {
#pragma unroll
    for (int o = 32; o > 0; o >>= 1) v = fmaxf(v, __shfl_down(v, o));
    __syncthreads();
    if ((threadIdx.x & 63) == 0) sh[threadIdx.x >> 6] = v;
    __syncthreads();
    return fmaxf(fmaxf(sh[0], sh[1]), fmaxf(sh[2], sh[3]));
}
__device__ inline float blockSum(float v, float* sh) {
#pragma unroll
    for (int o = 32; o > 0; o >>= 1) v += __shfl_down(v, o);
    __syncthreads();
    if ((threadIdx.x & 63) == 0) sh[threadIdx.x >> 6] = v;
    __syncthreads();
    return sh[0] + sh[1] + sh[2] + sh[3];
}

template<int NV, int NSPLIT>
__global__ __launch_bounds__(256) void k_softmax(const float* __restrict__ S,
                                                 u16* __restrict__ Pb,
                                                 const float* __restrict__ maskf,
                                                 const float* __restrict__ smed,
                                                 const float* __restrict__ smaxA,
                                                 const float* __restrict__ sminA,
                                                 int L)
{
    __shared__ float sred[4];
    const int bi = blockIdx.y, q = blockIdx.x;
    const size_t pstr = (size_t)Bb * L * L;
    const float* row = S + (size_t)bi * L * L + (size_t)q * L;
    u16* prow = Pb + (size_t)bi * L * L + (size_t)q * L;
    const float* mk  = maskf + bi * L;
    const float* s0p = smed  + bi * L;
    const float* s1p = smaxA + bi * L;
    const float* s2p = sminA + bi * L;
    const int tid = threadIdx.x;
    float a0[NV], a1[NV], a2[NV];
    float m0 = -3.4e38f, m1 = -3.4e38f, m2 = -3.4e38f;
#pragma unroll
    for (int e = 0; e < NV; ++e) {
        int k = e * 256 + tid;
        float sv = row[k];
#pragma unroll
        for (int s2 = 1; s2 < NSPLIT; ++s2) sv += row[(size_t)s2 * pstr + k];
        bool msk = mk[k] > 0.5f;
        float v0 = msk ? -1e9f : sv * s0p[k];
        float v1 = msk ? -1e9f : sv * s1p[k];
        float v2 = msk ? -1e9f : sv * s2p[k];
        a0[e] = v0; a1[e] = v1; a2[e] = v2;
        m0 = fmaxf(m0, v0); m1 = fmaxf(m1, v1); m2 = fmaxf(m2, v2);
    }
    m0 = blockMax(m0, sred); m1 = blockMax(m1, sred); m2 = blockMax(m2, sred);
    float l0 = 0.f, l1 = 0.f, l2 = 0.f;
#pragma unroll
    for (int e = 0; e < NV; ++e) {
        a0[e] = __expf(a0[e] - m0); l0 += a0[e];
        a1[e] = __expf(a1[e] - m1); l1 += a1[e];
        a2[e] = __expf(a2[e] - m2); l2 += a2[e];
    }
    l0 = blockSum(l0, sred); l1 = blockSum(l1, sred); l2 = blockSum(l2, sred);
    float c0 = 1.f / (3.f * l0), c1 = 1.f / (3.f * l1), c2 = 1.f / (3.f * l2);
#pragma unroll
    for (int e = 0; e < NV; ++e)
        prow[e * 256 + tid] = f2bf(a0[e] * c0 + a1[e] * c1 + a2[e] * c2);
}

// ---------------------------------------------------------------------------
// Y = P @ V (bf16 MFMA, V stored [F][L]), scatter into catbT[pix][cin] bf16.
// grid (F/128, L/128, Bb)
// ---------------------------------------------------------------------------
__global__ __launch_bounds__(256) void k_pv_mfma(const u16* __restrict__ Pb,
                                                 const u16* __restrict__ Vt,
                                                 u16* __restrict__ catbT,
                                                 int L, int F, int ps, int outn, int cbase)
{
    __shared__ u16 lAs[4096], lBs[4096];
    const int tid = threadIdx.x, wave = tid >> 6, lane = tid & 63;
    const int bi = blockIdx.z;
    f32x4 acc[4][4];
#pragma unroll
    for (int i = 0; i < 4; ++i)
#pragma unroll
        for (int j = 0; j < 4; ++j) acc[i][j] = (f32x4){0.f, 0.f, 0.f, 0.f};
    mfma_nt(Pb + (size_t)bi * L * L + (size_t)blockIdx.y * 128 * L, L,
            Vt + (size_t)bi * F * L + (size_t)blockIdx.x * 128 * L, L,
            L / 32, wave, lane, lAs, lBs, acc);
    const int wm = (wave >> 1) * 64, wn = (wave & 1) * 64;
    const int rb = (lane >> 4) * 4, cb = lane & 15;
    const int hw = ps * ps;
#pragma unroll
    for (int i = 0; i < 4; ++i)
#pragma unroll
        for (int reg = 0; reg < 4; ++reg) {
            int l = blockIdx.y * 128 + wm + i * 16 + rb + reg;
            int ti = l / (outn * outn); int rem = l % (outn * outn);
            int oh = rem / outn, ow = rem % outn;
            int n = bi * Tt + ti;
#pragma unroll
            for (int j = 0; j < 4; ++j) {
                int f = blockIdx.x * 128 + wn + j * 16 + cb;
                int c = cbase + f / hw, r = f % hw;
                int pix = (oh * ps + r / ps) * 64 + ow * ps + r % ps;
                catbT[((size_t)n * PIX + pix) * Dc + c] = f2bf(acc[i][j][reg]);
            }
        }
}

// ---------------------------------------------------------------------------
// Output conv 3x3 as 9-tap implicit NT GEMM over catbT; OOB lanes read a
// zero page (per-lane global source is legal with global_load_lds).
// grid (512 pixel tiles)
// ---------------------------------------------------------------------------
__global__ __launch_bounds__(256) void k_conv_mfma(const u16* __restrict__ catbT,
                                                   const u16* __restrict__ WoT,
                                                   const float* __restrict__ bo,
                                                   const u16* __restrict__ zp,
                                                   float* __restrict__ outp)
{
    __shared__ u16 lAs[4096], lBs[4096];
    const int tid = threadIdx.x, wave = tid >> 6, lane = tid & 63;
    const int pix0 = blockIdx.x * 128;
    const int r = lane >> 2;
    const int kq8 = ((lane & 3) ^ ((r >> 1) & 3)) * 8;   // swizzled source seg
    f32x4 acc[4][4];
#pragma unroll
    for (int i = 0; i < 4; ++i)
#pragma unroll
        for (int j = 0; j < 4; ++j) acc[i][j] = (f32x4){0.f, 0.f, 0.f, 0.f};
    for (int tap = 0; tap < 9; ++tap) {
        const int dy = tap / 3 - 1, dx = tap % 3 - 1;
        const u16* ga[2];
#pragma unroll
        for (int s = 0; s < 2; ++s) {
            int pg = pix0 + wave * 32 + r + s * 16;
            int n = pg >> 12, p = pg & 4095;
            int y = (p >> 6) + dy, xx = (p & 63) + dx;
            bool ok = (y >= 0 && y < 64 && xx >= 0 && xx < 64);
            ga[s] = ok ? catbT + ((size_t)(n << 12) + y * 64 + xx) * Dc + kq8 : zp;
        }
        const u16* gb = WoT + tap * 16384 + (size_t)(wave * 32 + r) * 128 + kq8;
        for (int kc = 0; kc < 4; ++kc) {
            __syncthreads();
            GLOAD16(ga[0] + kc * 32, lAs + wave * 1024);
            GLOAD16(ga[1] + kc * 32, lAs + wave * 1024 + 512);
            GLOAD16(gb + kc * 32, lBs + wave * 1024);
            GLOAD16(gb + 2048 + kc * 32, lBs + wave * 1024 + 512);
            __syncthreads();
            mfma_chunk(lAs, lBs, wave, lane, acc);
        }
    }
    const int wm = (wave >> 1) * 64, wn = (wave & 1) * 64;
    const int rb = (lane >> 4) * 4, cb = lane & 15;
#pragma unroll
    for (int i = 0; i < 4; ++i)
#pragma unroll
        for (int reg = 0; reg < 4; ++reg) {
            int pg = pix0 + wm + i * 16 + rb + reg;
            int n = pg >> 12, p = pg & 4095;
#pragma unroll
            for (int j = 0; j < 4; ++j) {
                int cout = wn + j * 16 + cb;
                float v = acc[i][j][reg] + bo[cout];
                v = (v >= 0.f) ? v : 0.2f * v;
                outp[((size_t)n * Dc + cout) * PIX + p] = v;
            }
        }
}

// ---------------------------------------------------------------------------
extern "C" void kernel_launch(void* const* d_in, const int* in_sizes, int n_in,
                              void* d_out, int out_size, void* d_ws, size_t ws_size,
                              hipStream_t stream)
{
    (void)in_sizes; (void)n_in; (void)out_size; (void)ws_size;
    const float* x    = (const float*)d_in[0];
    const float* mI   = (const float*)d_in[1];
    const float* dmap = (const float*)d_in[2];
    const float* wq   = (const float*)d_in[3];
    const float* bq   = (const float*)d_in[4];
    const float* wk   = (const float*)d_in[5];
    const float* bk   = (const float*)d_in[6];
    const float* wv   = (const float*)d_in[7];
    const float* bv   = (const float*)d_in[8];
    const float* wvle = (const float*)d_in[9];
    const float* bvle = (const float*)d_in[10];
    const float* wd1  = (const float*)d_in[11];
    const float* bd1  = (const float*)d_in[12];
    const float* wd2  = (const float*)d_in[13];
    const float* bd2  = (const float*)d_in[14];
    const float* wo   = (const float*)d_in[15];
    const float* bo   = (const float*)d_in[16];

    // workspace layout (~160 MB)
    char* w8 = (char*)d_ws;
    u16*   q_bf  = (u16*)(w8);                    // 16 MB each
    u16*   k_bf  = (u16*)(w8 + 0x1000000);
    u16*   v_bf  = (u16*)(w8 + 0x2000000);
    u16*   Xt    = (u16*)(w8 + 0x3000000);
    u16*   catbT = (u16*)(w8 + 0x4000000);
    u16*   Qp    = (u16*)(w8 + 0x5000000);        // 8 MB each
    u16*   Kp    = (u16*)(w8 + 0x5800000);
    u16*   Vt    = (u16*)(w8 + 0x6000000);
    float* Sb    = (float*)(w8 + 0x6800000);      // 32 MB (holds 8x2MB partials for i=1)
    u16*   Pb    = (u16*)(w8 + 0x8800000);        // 16 MB
    float* dep   = (float*)(w8 + 0x9800000);
    float* maskf = (float*)(w8 + 0x9840000);
    float* smed  = (float*)(w8 + 0x9844000);
    float* smaxA = (float*)(w8 + 0x9848000);
    float* sminA = (float*)(w8 + 0x984C000);
    u16*   Wqkv  = (u16*)(w8 + 0x9850000);
    u16*   WoT   = (u16*)(w8 + 0x9868000);
    u16*   zp    = (u16*)(w8 + 0x98B0000);
    float* outp  = (float*)d_out;

    hipMemcpyAsync(outp + 8388608, dmap, (size_t)16 * 65536 * sizeof(float),
                   hipMemcpyDeviceToDevice, stream);
    hipMemsetAsync(zp, 0, 256, stream);

    dim3 blk(256);
    k_prep<<<dim3(768), blk, 0, stream>>>(wq, wk, wv, wo, Wqkv, WoT);
    k_xt<<<dim3(64, 16), blk, 0, stream>>>(x, Xt);
    k_qkv_mfma<<<dim3(32, 3, 16), blk, 0, stream>>>(Wqkv, Xt, bq, bk, bv, q_bf, k_bf, v_bf);
    k_vdw<<<dim3(16, 128, 16), blk, 0, stream>>>(x, wvle, bvle, v_bf);
    k_depth<<<dim3(4, 4, 16), blk, 0, stream>>>(dmap, wd1, bd1, wd2, bd2, dep);

    for (int i = 0; i < 2; ++i) {
        const int ps = (i == 0) ? 4 : 8;
        const int outn = 64 / ps;
        const int L = Tt * outn * outn;        // 2048 / 512
        const int F = 64 * ps * ps;            // 1024 / 4096
        const int cbase = i * 64;
        const float scale = 1.0f / sqrtf((float)F);
        const int ksplit = (i == 0) ? 1 : 8;

        if (i == 0) k_stats2<4><<<dim3(Bb * L * 16 / 256), blk, 0, stream>>>(mI, dep, maskf, smed, smaxA, sminA, outn, L);
        else        k_stats2<8><<<dim3(Bb * L * 64 / 256), blk, 0, stream>>>(mI, dep, maskf, smed, smaxA, sminA, outn, L);

        const int pgrid = (int)(((size_t)Bb * L * F / 4 + 255) / 256);
        k_patch_bf<<<dim3(pgrid), blk, 0, stream>>>(q_bf, Qp, ps, outn, L, F, cbase);
        k_patch_bf<<<dim3(pgrid), blk, 0, stream>>>(k_bf, Kp, ps, outn, L, F, cbase);
        k_patchT<<<dim3(pgrid), blk, 0, stream>>>(v_bf, Vt, ps, outn, L, F, cbase);

        k_qkT_mfma<<<dim3(L / 128, L / 128, Bb * ksplit), blk, 0, stream>>>(Qp, Kp, Sb, L, F, ksplit, scale);

        if (i == 0) k_softmax<8, 1><<<dim3(L, Bb), blk, 0, stream>>>(Sb, Pb, maskf, smed, smaxA, sminA, L);
        else        k_softmax<2, 8><<<dim3(L, Bb), blk, 0, stream>>>(Sb, Pb, maskf, smed, smaxA, sminA, L);

        k_pv_mfma<<<dim3(F / 128, L / 128, Bb), blk, 0, stream>>>(Pb, Vt, catbT, L, F, ps, outn, cbase);
    }

    k_conv_mfma<<<dim3(512), blk, 0, stream>>>(catbT, WoT, bo, zp, outp);
}

// Round 4
// 545.239 us; speedup vs baseline: 4.3396x; 1.1987x over previous
//
#include <hip/hip_runtime.h>
#include <cmath>

typedef unsigned short u16;
typedef __attribute__((ext_vector_type(8))) __bf16 bf16x8;
typedef __attribute__((ext_vector_type(4))) float f32x4;

constexpr int Bb = 2, Tt = 8, Dc = 128, PIX = 4096; // b=2, c=128, 64x64 imgs

__device__ inline u16 f2bf(float f) {
    unsigned u = __builtin_bit_cast(unsigned, f);
    u += 0x7fffu + ((u >> 16) & 1u);
    return (u16)(u >> 16);
}
__device__ inline float bf2f(u16 h) {
    unsigned u = ((unsigned)h) << 16;
    return __builtin_bit_cast(float, u);
}

#define GLOAD16(gp, lp) __builtin_amdgcn_global_load_lds( \
    (const __attribute__((address_space(1))) void*)(const void*)(gp), \
    (__attribute__((address_space(3))) void*)(void*)(lp), 16, 0, 0)

// ---------------------------------------------------------------------------
// bf16 NT MFMA core: C(128x128) = A(128xK) * B(128xK)^T.
// LDS layout [row][kseg] with XOR swizzle: stored seg c holds global seg
// c ^ ((row>>1)&3); global_load_lds dest is lane*16B, so the swizzle is
// implemented by permuting each lane's GLOBAL source k-segment.
// ---------------------------------------------------------------------------
__device__ inline void mfma_chunk(const u16* lAs, const u16* lBs, int wave, int lane,
                                  f32x4 (&acc)[4][4])
{
    const int wm = (wave >> 1) * 64, wn = (wave & 1) * 64;
    const int fr = lane & 15;
    const int q4 = lane >> 4;                         // wanted global k-quarter
    const int sw = (q4 ^ ((fr >> 1) & 3)) * 8;        // swizzled storage seg
    bf16x8 av[4], bv[4];
#pragma unroll
    for (int i = 0; i < 4; ++i) av[i] = *(const bf16x8*)&lAs[(wm + i * 16 + fr) * 32 + sw];
#pragma unroll
    for (int j = 0; j < 4; ++j) bv[j] = *(const bf16x8*)&lBs[(wn + j * 16 + fr) * 32 + sw];
#pragma unroll
    for (int i = 0; i < 4; ++i)
#pragma unroll
        for (int j = 0; j < 4; ++j)
            acc[i][j] = __builtin_amdgcn_mfma_f32_16x16x32_bf16(av[i], bv[j], acc[i][j], 0, 0, 0);
}

__device__ inline void mfma_nt(const u16* A, int ldkA, const u16* B, int ldkB,
                               int kChunks, int wave, int lane,
                               u16* lAs, u16* lBs, f32x4 (&acc)[4][4])
{
    const int r = lane >> 2;                              // row within 16-group
    const int kq8 = ((lane & 3) ^ ((r >> 1) & 3)) * 8;    // swizzled source seg
    const u16* ga0 = A + (size_t)(wave * 32 + r) * ldkA + kq8;
    const u16* ga1 = ga0 + (size_t)16 * ldkA;
    const u16* gb0 = B + (size_t)(wave * 32 + r) * ldkB + kq8;
    const u16* gb1 = gb0 + (size_t)16 * ldkB;
    for (int kb = 0; kb < kChunks; ++kb) {
        __syncthreads();                       // WAR: prior chunk's ds_reads done
        GLOAD16(ga0 + kb * 32, lAs + wave * 1024);
        GLOAD16(ga1 + kb * 32, lAs + wave * 1024 + 512);
        GLOAD16(gb0 + kb * 32, lBs + wave * 1024);
        GLOAD16(gb1 + kb * 32, lBs + wave * 1024 + 512);
        __syncthreads();                       // drains vmcnt(0) before barrier
        mfma_chunk(lAs, lBs, wave, lane, acc);
    }
}

// ---------------------------------------------------------------------------
// Weight prep: Wqkv[3*128][128] bf16 stacked; WoT[tap][cout][cin] bf16.
// ---------------------------------------------------------------------------
__global__ void k_prep(const float* __restrict__ wq, const float* __restrict__ wk,
                       const float* __restrict__ wv, const float* __restrict__ wo,
                       u16* __restrict__ Wqkv, u16* __restrict__ WoT)
{
    int idx = blockIdx.x * 256 + threadIdx.x;
    if (idx < 49152) {
        const float* w = idx < 16384 ? wq : (idx < 32768 ? wk : wv);
        Wqkv[idx] = f2bf(w[idx & 16383]);
    }
    int j = idx - 49152;
    if (j >= 0 && j < 147456) {
        int tap = j / 16384, rem = j % 16384;  // rem = cout*128+cin
        WoT[j] = f2bf(wo[(size_t)rem * 9 + tap]);
    }
}

// ---------------------------------------------------------------------------
// Xt[n][pix][cin] bf16 from x[n][cin][pix] fp32 (LDS transpose, 64-pix tiles)
// ---------------------------------------------------------------------------
__global__ __launch_bounds__(256) void k_xt(const float* __restrict__ x, u16* __restrict__ Xt)
{
    __shared__ float ls[128 * 65];
    const int n = blockIdx.y, pix0 = blockIdx.x * 64;
#pragma unroll
    for (int rep = 0; rep < 32; ++rep) {
        int idx = rep * 256 + threadIdx.x;
        int cin = idx >> 6, p = idx & 63;
        ls[cin * 65 + p] = x[((size_t)n * Dc + cin) * PIX + pix0 + p];
    }
    __syncthreads();
#pragma unroll
    for (int rep = 0; rep < 32; ++rep) {
        int idx = rep * 256 + threadIdx.x;
        int p = idx >> 7, cin = idx & 127;
        Xt[((size_t)n * PIX + pix0 + p) * Dc + cin] = f2bf(ls[cin * 65 + p]);
    }
}

// ---------------------------------------------------------------------------
// Fused QKV: C[384][4096] = Wqkv * Xt^T per image; bf16 out + bias, routed.
// grid (32 pixtiles, 3 Mtiles, 16 imgs)
// ---------------------------------------------------------------------------
__global__ __launch_bounds__(256) void k_qkv_mfma(const u16* __restrict__ Wqkv,
                                                  const u16* __restrict__ Xt,
                                                  const float* __restrict__ bq,
                                                  const float* __restrict__ bk,
                                                  const float* __restrict__ bv,
                                                  u16* __restrict__ q_bf,
                                                  u16* __restrict__ k_bf,
                                                  u16* __restrict__ v_bf)
{
    __shared__ u16 lAs[4096], lBs[4096];
    const int tid = threadIdx.x, wave = tid >> 6, lane = tid & 63;
    const int mt = blockIdx.y, n = blockIdx.z, px0 = blockIdx.x * 128;
    f32x4 acc[4][4];
#pragma unroll
    for (int i = 0; i < 4; ++i)
#pragma unroll
        for (int j = 0; j < 4; ++j) acc[i][j] = (f32x4){0.f, 0.f, 0.f, 0.f};
    mfma_nt(Wqkv + (size_t)mt * 128 * 128, 128,
            Xt + ((size_t)n * PIX + px0) * 128, 128, 4, wave, lane, lAs, lBs, acc);
    const int wm = (wave >> 1) * 64, wn = (wave & 1) * 64;
    const int rb = (lane >> 4) * 4, cb = lane & 15;
#pragma unroll
    for (int i = 0; i < 4; ++i)
#pragma unroll
        for (int reg = 0; reg < 4; ++reg) {
            int gmg = mt * 128 + wm + i * 16 + rb + reg;     // stacked cout 0..383
            int sel = gmg >> 7, c = gmg & 127;
            float bias = (sel == 0 ? bq : sel == 1 ? bk : bv)[c];
            u16* dst = (sel == 0 ? q_bf : sel == 1 ? k_bf : v_bf);
#pragma unroll
            for (int j = 0; j < 4; ++j) {
                int pix = px0 + wn + j * 16 + cb;
                dst[((size_t)n * Dc + c) * PIX + pix] = f2bf(acc[i][j][reg] + bias);
            }
        }
}

// ---------------------------------------------------------------------------
// depthwise 3x3 add into bf16 v_all. grid (16, 128, 16)
// ---------------------------------------------------------------------------
__global__ __launch_bounds__(256) void k_vdw(const float* __restrict__ X,
                                             const float* __restrict__ wvle,
                                             const float* __restrict__ bvle,
                                             u16* __restrict__ v_bf)
{
    const int n = blockIdx.z, c = blockIdx.y;
    const int p = blockIdx.x * 256 + threadIdx.x;
    const int y = p >> 6, x = p & 63;
    const float* xp = X + ((size_t)n * Dc + c) * PIX;
    const float* w  = wvle + c * 9;
    float s = bvle[c];
#pragma unroll
    for (int ky = 0; ky < 3; ++ky) {
        int yy = y + ky - 1;
        if (yy < 0 || yy >= 64) continue;
#pragma unroll
        for (int kx = 0; kx < 3; ++kx) {
            int xx = x + kx - 1;
            if (xx < 0 || xx >= 64) continue;
            s += w[ky * 3 + kx] * xp[yy * 64 + xx];
        }
    }
    size_t idx = ((size_t)n * Dc + c) * PIX + p;
    v_bf[idx] = f2bf(bf2f(v_bf[idx]) + s);
}

// ---------------------------------------------------------------------------
// Depth path, kernel 1: d1[n][c][128][128] = relu(conv(dm, wd1, s2, p1)) bf16.
// Block = 8x64 output tile; dm tile staged in LDS ONCE, each thread's 18 taps
// hoisted to REGISTERS, then the 128-channel loop is pure FMA + stores.
// grid (32 = 16 ytiles x 2 xhalf, 16 n). Replaces the fused k_depth (179 us,
// 1 block/CU, 1.86e7 LDS conflicts): d1's 67 MB HBM round-trip ~22 us beats
// 150+ us of serialized LDS-bound compute.
// ---------------------------------------------------------------------------
__global__ __launch_bounds__(256) void k_d1(const float* __restrict__ dm,
                                            const float* __restrict__ wd1,
                                            const float* __restrict__ bd1,
                                            u16* __restrict__ d1b)
{
    __shared__ float ls[17 * 132];
    const int n = blockIdx.y;
    const int yt = blockIdx.x >> 1, xh = blockIdx.x & 1;
    const int Y0 = yt * 8;
    const int tid = threadIdx.x;
    const float* dmp = dm + (size_t)n * 65536;
    // stage input rows 2Y0-1..2Y0+15, cols 128xh-1..128xh+127 (cl 0..128)
    for (int idx = tid; idx < 17 * 132; idx += 256) {
        int row = idx / 132, cl = idx % 132;
        int gr = 2 * Y0 - 1 + row;
        int gc = 128 * xh - 1 + cl;
        float v = 0.f;
        if (gr >= 0 && gr < 256 && gc >= 0 && gc < 256 && cl < 129) v = dmp[gr * 256 + gc];
        ls[idx] = v;
    }
    __syncthreads();
    const int Xl = tid & 63;
    const int Yl0 = tid >> 6;                 // rows Yl0 and Yl0+4
    float in0[9], in1[9];
#pragma unroll
    for (int jy = 0; jy < 3; ++jy)
#pragma unroll
        for (int jx = 0; jx < 3; ++jx) {
            in0[jy * 3 + jx] = ls[(2 * Yl0 + jy) * 132 + 2 * Xl + jx];
            in1[jy * 3 + jx] = ls[(2 * (Yl0 + 4) + jy) * 132 + 2 * Xl + jx];
        }
    const int X = 64 * xh + Xl;
    u16* outbase = d1b + (size_t)n * Dc * 16384 + (size_t)Y0 * 128 + X;
    for (int c = 0; c < 128; ++c) {
        const float* w1 = wd1 + c * 9;        // uniform -> s_load
        float a0 = bd1[c], a1 = a0;
#pragma unroll
        for (int t = 0; t < 9; ++t) { a0 += w1[t] * in0[t]; a1 += w1[t] * in1[t]; }
        u16* ob = outbase + (size_t)c * 16384;
        ob[(size_t)Yl0 * 128]       = f2bf(fmaxf(a0, 0.f));
        ob[(size_t)(Yl0 + 4) * 128] = f2bf(fmaxf(a1, 0.f));
    }
}

// ---------------------------------------------------------------------------
// Depth path, kernel 2: partial conv2 over 16-channel groups.
// part[cg][n][64*64] = sum_{c in cg} wd2[c] (*) relu-d1[c] (stride2, pad1)
// grid (4 ytiles, 16 n, 8 cg); per channel: stage 33x128 bf16 slice (uint4),
// each thread accumulates 4 consecutive output rows in registers.
// ---------------------------------------------------------------------------
__global__ __launch_bounds__(256) void k_d2p(const u16* __restrict__ d1b,
                                             const float* __restrict__ wd2,
                                             float* __restrict__ part)
{
    __shared__ u16 ls[33 * 136];              // payload at cl 8..135, zero at cl 7
    const int yt = blockIdx.x, n = blockIdx.y, cg = blockIdx.z;
    const int tid = threadIdx.x;
    const int y0 = yt * 16;
    if (tid < 33) ls[tid * 136 + 7] = 0;
    const int x = tid & 63;
    const int yl0 = (tid >> 6) * 4;           // 4 consecutive rows per thread
    float acc[4] = {0.f, 0.f, 0.f, 0.f};
    for (int c = 0; c < 16; ++c) {
        const u16* src = d1b + ((size_t)n * Dc + cg * 16 + c) * 16384;
        __syncthreads();                      // WAR vs prior iter reads (covers cl7 init)
        for (int idx = tid; idx < 33 * 16; idx += 256) {
            int row = idx >> 4, s = idx & 15;
            int gr = 2 * y0 - 1 + row;
            uint4 v = make_uint4(0, 0, 0, 0);
            if (gr >= 0 && gr < 128) v = *(const uint4*)(src + gr * 128 + s * 8);
            *(uint4*)&ls[row * 136 + 8 + s * 8] = v;
        }
        __syncthreads();
        const float* w2 = wd2 + (cg * 16 + c) * 9;   // uniform -> s_load
        float w[9];
#pragma unroll
        for (int t = 0; t < 9; ++t) w[t] = w2[t];
#pragma unroll
        for (int r = 0; r < 4; ++r) {
            int yl = yl0 + r;
#pragma unroll
            for (int ky = 0; ky < 3; ++ky) {
                const u16* rp = &ls[(2 * yl + ky) * 136 + 2 * x + 7];
                float v0 = bf2f(rp[0]);
                unsigned pr = *(const unsigned*)(rp + 1);   // 4B-aligned pair
                float v1 = bf2f((u16)(pr & 0xffffu));
                float v2 = bf2f((u16)(pr >> 16));
                acc[r] += w[ky * 3 + 0] * v0 + w[ky * 3 + 1] * v1 + w[ky * 3 + 2] * v2;
            }
        }
    }
    float* pp = part + ((size_t)cg * 16 + n) * PIX;
#pragma unroll
    for (int r = 0; r < 4; ++r)
        pp[(y0 + yl0 + r) * 64 + x] = acc[r];
}

// Depth path, kernel 3: dep = relu(sum_cg part + bd2). grid (256)
__global__ void k_dfin(const float* __restrict__ part, const float* __restrict__ bd2,
                       float* __restrict__ dep)
{
    int idx = blockIdx.x * 256 + threadIdx.x;
    float s = bd2[0];
#pragma unroll
    for (int cg = 0; cg < 8; ++cg) s += part[(size_t)cg * 65536 + idx];
    dep[idx] = fmaxf(s, 0.f);
}

// ---------------------------------------------------------------------------
// Wave-parallel per-token stats (min/max/mask butterfly, exact median rank).
// ---------------------------------------------------------------------------
template<int PS>
__global__ __launch_bounds__(256) void k_stats2(const float* __restrict__ mI,
                                                const float* __restrict__ dep,
                                                float* __restrict__ maskf,
                                                float* __restrict__ smed,
                                                float* __restrict__ smaxA,
                                                float* __restrict__ sminA,
                                                int outn, int L)
{
    constexpr int HW = PS * PS;              // 16 or 64
    constexpr int TPB = 256 / HW;            // tokens per block
    const int tok = blockIdx.x * TPB + threadIdx.x / HW;
    const int el  = threadIdx.x % HW;
    if (tok >= Bb * L) return;
    const int bi = tok / L, l = tok % L;
    const int ti = l / (outn * outn); const int rem = l % (outn * outn);
    const int oh = rem / outn, ow = rem % outn;
    const int n = bi * Tt + ti;
    const int py = el / PS, px = el % PS;
    const size_t off = (size_t)n * PIX + (size_t)(oh * PS + py) * 64 + ow * PS + px;
    const float mv = mI[off];
    const float dv = dep[off];
    float msum = mv, vmin = dv, vmax = dv;
#pragma unroll
    for (int o = HW / 2; o > 0; o >>= 1) {
        msum += __shfl_xor(msum, o);
        vmin = fminf(vmin, __shfl_xor(vmin, o));
        vmax = fmaxf(vmax, __shfl_xor(vmax, o));
    }
    const int gbase = (threadIdx.x & 63) & ~(HW - 1);
    int cl = 0, ce = 0;
#pragma unroll
    for (int b2 = 0; b2 < HW; ++b2) {
        float vb = __shfl(dv, gbase + b2);
        cl += (vb < dv);
        ce += (vb == dv);
    }
    constexpr int kk = (HW - 1) / 2;
    if (el == 0) {
        maskf[tok] = (msum / (float)HW > 0.5f) ? 1.f : 0.f;
        smaxA[tok] = 1.f / (1.f + __expf(-vmax));
        sminA[tok] = 1.f / (1.f + __expf(-vmin));
    }
    if (cl <= kk && kk < cl + ce)
        smed[tok] = 1.f / (1.f + __expf(-dv));
}

// ---------------------------------------------------------------------------
// Patch-extract bf16 -> bf16 [bi][l][f], 4 elements (=4 px) per thread.
// ---------------------------------------------------------------------------
__global__ void k_patch_bf(const u16* __restrict__ src, u16* __restrict__ dst,
                           int ps, int outn, int L, int F, int cbase)
{
    size_t idx = (size_t)blockIdx.x * 256 + threadIdx.x;
    size_t total = (size_t)Bb * L * F / 4;
    if (idx >= total) return;
    int f0 = (int)((idx * 4) % F);
    size_t t2 = (idx * 4) / F;
    int l = (int)(t2 % L);
    int bi = (int)(t2 / L);
    int hw = ps * ps;
    int ti = l / (outn * outn); int rem = l % (outn * outn);
    int oh = rem / outn, ow = rem % outn;
    int c = f0 / hw, r = f0 % hw;
    int py = r / ps, px = r % ps;
    int n = bi * Tt + ti;
    size_t si = ((size_t)n * Dc + cbase + c) * PIX + (oh * ps + py) * 64 + ow * ps + px;
    *(uint2*)&dst[((size_t)bi * L + l) * F + f0] = *(const uint2*)&src[si];
}

// V transposed patch: Vt[bi][f][l] bf16. 4 consecutive l per thread.
__global__ void k_patchT(const u16* __restrict__ v_bf, u16* __restrict__ Vt,
                         int ps, int outn, int L, int F, int cbase)
{
    size_t idx = (size_t)blockIdx.x * 256 + threadIdx.x;
    size_t total = (size_t)Bb * F * L / 4;
    if (idx >= total) return;
    int l0 = (int)((idx * 4) % L);
    size_t t2 = (idx * 4) / L;
    int f = (int)(t2 % F);
    int bi = (int)(t2 / F);
    int hw = ps * ps;
    int c = cbase + f / hw, r = f % hw;
    int py = r / ps, px = r % ps;
    int ti = l0 / (outn * outn); int rem = l0 % (outn * outn);
    int oh = rem / outn, ow0 = rem % outn;
    size_t base = ((size_t)(bi * Tt + ti) * Dc + c) * PIX + (oh * ps + py) * 64 + px;
    u16 out4[4];
#pragma unroll
    for (int e = 0; e < 4; ++e) out4[e] = v_bf[base + (size_t)(ow0 + e) * ps];
    *(uint2*)&Vt[((size_t)bi * F + f) * L + l0] = *(uint2*)out4;
}

// ---------------------------------------------------------------------------
// S = scale * Q K^T (bf16 MFMA), fp32 out. Split-K writes DISJOINT partial
// buffers (S + ks*Bb*L*L); softmax sums the partials. No atomics.
// ---------------------------------------------------------------------------
__global__ __launch_bounds__(256) void k_qkT_mfma(const u16* __restrict__ Qp,
                                                  const u16* __restrict__ Kp,
                                                  float* __restrict__ S,
                                                  int L, int F, int ksplit, float scale)
{
    __shared__ u16 lAs[4096], lBs[4096];
    const int tid = threadIdx.x, wave = tid >> 6, lane = tid & 63;
    const int bi = blockIdx.z / ksplit, ks = blockIdx.z % ksplit;
    const int kf = F / ksplit;
    f32x4 acc[4][4];
#pragma unroll
    for (int i = 0; i < 4; ++i)
#pragma unroll
        for (int j = 0; j < 4; ++j) acc[i][j] = (f32x4){0.f, 0.f, 0.f, 0.f};
    mfma_nt(Qp + (size_t)bi * L * F + (size_t)blockIdx.y * 128 * F + (size_t)ks * kf, F,
            Kp + (size_t)bi * L * F + (size_t)blockIdx.x * 128 * F + (size_t)ks * kf, F,
            kf / 32, wave, lane, lAs, lBs, acc);
    const int wm = (wave >> 1) * 64, wn = (wave & 1) * 64;
    const int rb = (lane >> 4) * 4, cb = lane & 15;
    float* Cp = S + ((size_t)ks * Bb + bi) * L * L;
#pragma unroll
    for (int i = 0; i < 4; ++i)
#pragma unroll
        for (int reg = 0; reg < 4; ++reg) {
            int gm = blockIdx.y * 128 + wm + i * 16 + rb + reg;
#pragma unroll
            for (int j = 0; j < 4; ++j) {
                int gn = blockIdx.x * 128 + wn + j * 16 + cb;
                Cp[(size_t)gm * L + gn] = acc[i][j][reg] * scale;
            }
        }
}

// ---------------------------------------------------------------------------
// 3-head softmax (sums NSPLIT partial S buffers), combined probs -> bf16 Pb.
// ---------------------------------------------------------------------------
__device__ inline float blockMax(float v, float* sh) {
#pragma unroll
    for (int o = 32; o > 0; o >>= 1) v = fmaxf(v, __shfl_down(v, o));
    __syncthreads();
    if ((threadIdx.x & 63) == 0) sh[threadIdx.x >> 6] = v;
    __syncthreads();
    return fmaxf(fmaxf(sh[0], sh[1]), fmaxf(sh[2], sh[3]));
}
__device__ inline float blockSum(float v, float* sh) {
#pragma unroll
    for (int o = 32; o > 0; o >>= 1) v += __shfl_down(v, o);
    __syncthreads();
    if ((threadIdx.x & 63) == 0) sh[threadIdx.x >> 6] = v;
    __syncthreads();
    return sh[0] + sh[1] + sh[2] + sh[3];
}

template<int NV, int NSPLIT>
__global__ __launch_bounds__(256) void k_softmax(const float* __restrict__ S,
                                                 u16* __restrict__ Pb,
                                                 const float* __restrict__ maskf,
                                                 const float* __restrict__ smed,
                                                 const float* __restrict__ smaxA,
                                                 const float* __restrict__ sminA,
                                                 int L)
{
    __shared__ float sred[4];
    const int bi = blockIdx.y, q = blockIdx.x;
    const size_t pstr = (size_t)Bb * L * L;
    const float* row = S + (size_t)bi * L * L + (size_t)q * L;
    u16* prow = Pb + (size_t)bi * L * L + (size_t)q * L;
    const float* mk  = maskf + bi * L;
    const float* s0p = smed  + bi * L;
    const float* s1p = smaxA + bi * L;
    const float* s2p = sminA + bi * L;
    const int tid = threadIdx.x;
    float a0[NV], a1[NV], a2[NV];
    float m0 = -3.4e38f, m1 = -3.4e38f, m2 = -3.4e38f;
#pragma unroll
    for (int e = 0; e < NV; ++e) {
        int k = e * 256 + tid;
        float sv = row[k];
#pragma unroll
        for (int s2 = 1; s2 < NSPLIT; ++s2) sv += row[(size_t)s2 * pstr + k];
        bool msk = mk[k] > 0.5f;
        float v0 = msk ? -1e9f : sv * s0p[k];
        float v1 = msk ? -1e9f : sv * s1p[k];
        float v2 = msk ? -1e9f : sv * s2p[k];
        a0[e] = v0; a1[e] = v1; a2[e] = v2;
        m0 = fmaxf(m0, v0); m1 = fmaxf(m1, v1); m2 = fmaxf(m2, v2);
    }
    m0 = blockMax(m0, sred); m1 = blockMax(m1, sred); m2 = blockMax(m2, sred);
    float l0 = 0.f, l1 = 0.f, l2 = 0.f;
#pragma unroll
    for (int e = 0; e < NV; ++e) {
        a0[e] = __expf(a0[e] - m0); l0 += a0[e];
        a1[e] = __expf(a1[e] - m1); l1 += a1[e];
        a2[e] = __expf(a2[e] - m2); l2 += a2[e];
    }
    l0 = blockSum(l0, sred); l1 = blockSum(l1, sred); l2 = blockSum(l2, sred);
    float c0 = 1.f / (3.f * l0), c1 = 1.f / (3.f * l1), c2 = 1.f / (3.f * l2);
#pragma unroll
    for (int e = 0; e < NV; ++e)
        prow[e * 256 + tid] = f2bf(a0[e] * c0 + a1[e] * c1 + a2[e] * c2);
}

// ---------------------------------------------------------------------------
// Y = P @ V (bf16 MFMA, V stored [F][L]), scatter into catbT[pix][cin] bf16.
// ---------------------------------------------------------------------------
__global__ __launch_bounds__(256) void k_pv_mfma(const u16* __restrict__ Pb,
                                                 const u16* __restrict__ Vt,
                                                 u16* __restrict__ catbT,
                                                 int L, int F, int ps, int outn, int cbase)
{
    __shared__ u16 lAs[4096], lBs[4096];
    const int tid = threadIdx.x, wave = tid >> 6, lane = tid & 63;
    const int bi = blockIdx.z;
    f32x4 acc[4][4];
#pragma unroll
    for (int i = 0; i < 4; ++i)
#pragma unroll
        for (int j = 0; j < 4; ++j) acc[i][j] = (f32x4){0.f, 0.f, 0.f, 0.f};
    mfma_nt(Pb + (size_t)bi * L * L + (size_t)blockIdx.y * 128 * L, L,
            Vt + (size_t)bi * F * L + (size_t)blockIdx.x * 128 * L, L,
            L / 32, wave, lane, lAs, lBs, acc);
    const int wm = (wave >> 1) * 64, wn = (wave & 1) * 64;
    const int rb = (lane >> 4) * 4, cb = lane & 15;
    const int hw = ps * ps;
#pragma unroll
    for (int i = 0; i < 4; ++i)
#pragma unroll
        for (int reg = 0; reg < 4; ++reg) {
            int l = blockIdx.y * 128 + wm + i * 16 + rb + reg;
            int ti = l / (outn * outn); int rem = l % (outn * outn);
            int oh = rem / outn, ow = rem % outn;
            int n = bi * Tt + ti;
#pragma unroll
            for (int j = 0; j < 4; ++j) {
                int f = blockIdx.x * 128 + wn + j * 16 + cb;
                int c = cbase + f / hw, r = f % hw;
                int pix = (oh * ps + r / ps) * 64 + ow * ps + r % ps;
                catbT[((size_t)n * PIX + pix) * Dc + c] = f2bf(acc[i][j][reg]);
            }
        }
}

// ---------------------------------------------------------------------------
// Output conv 3x3 as 9-tap implicit NT GEMM over catbT; OOB lanes read a
// zero page. grid (512 pixel tiles)
// ---------------------------------------------------------------------------
__global__ __launch_bounds__(256) void k_conv_mfma(const u16* __restrict__ catbT,
                                                   const u16* __restrict__ WoT,
                                                   const float* __restrict__ bo,
                                                   const u16* __restrict__ zp,
                                                   float* __restrict__ outp)
{
    __shared__ u16 lAs[4096], lBs[4096];
    const int tid = threadIdx.x, wave = tid >> 6, lane = tid & 63;
    const int pix0 = blockIdx.x * 128;
    const int r = lane >> 2;
    const int kq8 = ((lane & 3) ^ ((r >> 1) & 3)) * 8;   // swizzled source seg
    f32x4 acc[4][4];
#pragma unroll
    for (int i = 0; i < 4; ++i)
#pragma unroll
        for (int j = 0; j < 4; ++j) acc[i][j] = (f32x4){0.f, 0.f, 0.f, 0.f};
    for (int tap = 0; tap < 9; ++tap) {
        const int dy = tap / 3 - 1, dx = tap % 3 - 1;
        const u16* ga[2];
#pragma unroll
        for (int s = 0; s < 2; ++s) {
            int pg = pix0 + wave * 32 + r + s * 16;
            int n = pg >> 12, p = pg & 4095;
            int y = (p >> 6) + dy, xx = (p & 63) + dx;
            bool ok = (y >= 0 && y < 64 && xx >= 0 && xx < 64);
            ga[s] = ok ? catbT + ((size_t)(n << 12) + y * 64 + xx) * Dc + kq8 : zp;
        }
        const u16* gb = WoT + tap * 16384 + (size_t)(wave * 32 + r) * 128 + kq8;
        for (int kc = 0; kc < 4; ++kc) {
            __syncthreads();
            GLOAD16(ga[0] + kc * 32, lAs + wave * 1024);
            GLOAD16(ga[1] + kc * 32, lAs + wave * 1024 + 512);
            GLOAD16(gb + kc * 32, lBs + wave * 1024);
            GLOAD16(gb + 2048 + kc * 32, lBs + wave * 1024 + 512);
            __syncthreads();
            mfma_chunk(lAs, lBs, wave, lane, acc);
        }
    }
    const int wm = (wave >> 1) * 64, wn = (wave & 1) * 64;
    const int rb = (lane >> 4) * 4, cb = lane & 15;
#pragma unroll
    for (int i = 0; i < 4; ++i)
#pragma unroll
        for (int reg = 0; reg < 4; ++reg) {
            int pg = pix0 + wm + i * 16 + rb + reg;
            int n = pg >> 12, p = pg & 4095;
#pragma unroll
            for (int j = 0; j < 4; ++j) {
                int cout = wn + j * 16 + cb;
                float v = acc[i][j][reg] + bo[cout];
                v = (v >= 0.f) ? v : 0.2f * v;
                outp[((size_t)n * Dc + cout) * PIX + p] = v;
            }
        }
}

// ---------------------------------------------------------------------------
extern "C" void kernel_launch(void* const* d_in, const int* in_sizes, int n_in,
                              void* d_out, int out_size, void* d_ws, size_t ws_size,
                              hipStream_t stream)
{
    (void)in_sizes; (void)n_in; (void)out_size; (void)ws_size;
    const float* x    = (const float*)d_in[0];
    const float* mI   = (const float*)d_in[1];
    const float* dmap = (const float*)d_in[2];
    const float* wq   = (const float*)d_in[3];
    const float* bq   = (const float*)d_in[4];
    const float* wk   = (const float*)d_in[5];
    const float* bk   = (const float*)d_in[6];
    const float* wv   = (const float*)d_in[7];
    const float* bv   = (const float*)d_in[8];
    const float* wvle = (const float*)d_in[9];
    const float* bvle = (const float*)d_in[10];
    const float* wd1  = (const float*)d_in[11];
    const float* bd1  = (const float*)d_in[12];
    const float* wd2  = (const float*)d_in[13];
    const float* bd2  = (const float*)d_in[14];
    const float* wo   = (const float*)d_in[15];
    const float* bo   = (const float*)d_in[16];

    // workspace layout (~162 MB)
    char* w8 = (char*)d_ws;
    u16*   q_bf  = (u16*)(w8);                    // 16 MB each
    u16*   k_bf  = (u16*)(w8 + 0x1000000);
    u16*   v_bf  = (u16*)(w8 + 0x2000000);
    u16*   Xt    = (u16*)(w8 + 0x3000000);
    u16*   catbT = (u16*)(w8 + 0x4000000);
    u16*   Qp    = (u16*)(w8 + 0x5000000);        // 8 MB each
    u16*   Kp    = (u16*)(w8 + 0x5800000);
    u16*   Vt    = (u16*)(w8 + 0x6000000);
    float* Sb    = (float*)(w8 + 0x6800000);      // 32 MB (8x2MB partials for i=1)
    u16*   Pb    = (u16*)(w8 + 0x8800000);        // 16 MB
    // d1b (67 MB) ALIASES Qp..Pb: depth path runs strictly before the attn loop
    u16*   d1b   = (u16*)(w8 + 0x5000000);
    float* dep   = (float*)(w8 + 0x9800000);
    float* maskf = (float*)(w8 + 0x9840000);
    float* smed  = (float*)(w8 + 0x9844000);
    float* smaxA = (float*)(w8 + 0x9848000);
    float* sminA = (float*)(w8 + 0x984C000);
    u16*   Wqkv  = (u16*)(w8 + 0x9850000);
    u16*   WoT   = (u16*)(w8 + 0x9868000);
    u16*   zp    = (u16*)(w8 + 0x98B0000);
    float* part  = (float*)(w8 + 0x98C0000);      // 2 MB
    float* outp  = (float*)d_out;

    hipMemcpyAsync(outp + 8388608, dmap, (size_t)16 * 65536 * sizeof(float),
                   hipMemcpyDeviceToDevice, stream);
    hipMemsetAsync(zp, 0, 256, stream);

    dim3 blk(256);
    // depth path first (d1b aliases attention scratch)
    k_d1<<<dim3(32, 16), blk, 0, stream>>>(dmap, wd1, bd1, d1b);
    k_d2p<<<dim3(4, 16, 8), blk, 0, stream>>>(d1b, wd2, part);
    k_dfin<<<dim3(256), blk, 0, stream>>>(part, bd2, dep);

    k_prep<<<dim3(768), blk, 0, stream>>>(wq, wk, wv, wo, Wqkv, WoT);
    k_xt<<<dim3(64, 16), blk, 0, stream>>>(x, Xt);
    k_qkv_mfma<<<dim3(32, 3, 16), blk, 0, stream>>>(Wqkv, Xt, bq, bk, bv, q_bf, k_bf, v_bf);
    k_vdw<<<dim3(16, 128, 16), blk, 0, stream>>>(x, wvle, bvle, v_bf);

    for (int i = 0; i < 2; ++i) {
        const int ps = (i == 0) ? 4 : 8;
        const int outn = 64 / ps;
        const int L = Tt * outn * outn;        // 2048 / 512
        const int F = 64 * ps * ps;            // 1024 / 4096
        const int cbase = i * 64;
        const float scale = 1.0f / sqrtf((float)F);
        const int ksplit = (i == 0) ? 1 : 8;

        if (i == 0) k_stats2<4><<<dim3(Bb * L * 16 / 256), blk, 0, stream>>>(mI, dep, maskf, smed, smaxA, sminA, outn, L);
        else        k_stats2<8><<<dim3(Bb * L * 64 / 256), blk, 0, stream>>>(mI, dep, maskf, smed, smaxA, sminA, outn, L);

        const int pgrid = (int)(((size_t)Bb * L * F / 4 + 255) / 256);
        k_patch_bf<<<dim3(pgrid), blk, 0, stream>>>(q_bf, Qp, ps, outn, L, F, cbase);
        k_patch_bf<<<dim3(pgrid), blk, 0, stream>>>(k_bf, Kp, ps, outn, L, F, cbase);
        k_patchT<<<dim3(pgrid), blk, 0, stream>>>(v_bf, Vt, ps, outn, L, F, cbase);

        k_qkT_mfma<<<dim3(L / 128, L / 128, Bb * ksplit), blk, 0, stream>>>(Qp, Kp, Sb, L, F, ksplit, scale);

        if (i == 0) k_softmax<8, 1><<<dim3(L, Bb), blk, 0, stream>>>(Sb, Pb, maskf, smed, smaxA, sminA, L);
        else        k_softmax<2, 8><<<dim3(L, Bb), blk, 0, stream>>>(Sb, Pb, maskf, smed, smaxA, sminA, L);

        k_pv_mfma<<<dim3(F / 128, L / 128, Bb), blk, 0, stream>>>(Pb, Vt, catbT, L, F, ps, outn, cbase);
    }

    k_conv_mfma<<<dim3(512), blk, 0, stream>>>(catbT, WoT, bo, zp, outp);
}